// Round 3
// baseline (254.869 us; speedup 1.0000x reference)
//
#include <hip/hip_runtime.h>
#include <math.h>

// Problem constants
#define BATCH 64
#define NPTS  2048
// ws float offsets
#define OFF_M   0        // [64][61]  M[b][c*6+a], Sdw at [b][60]
#define OFF_T2  4096     // [64][18]  T2[m][a*3+j]
#define OFF_V   8192     // TRANSPOSED: Vt[v][ma] = [128][384]
#define OFF_Z   73728    // [64][128] z (bias-init + atomic partials)
#define OFF_SQ  110592   // S[64], Q[64], ticket@+128(int), flag@+192(int)
#define OFF_SO  176128   // (unused now)

// ---------------------------------------------------------------------------
// k_wa: blocks 0..191   fold-V (LDS-tiled, 2 ma per block)
//       blocks 192..209 fold-T2 (one (a,j) pair per block, col staged in LDS)
//       blocks 210..273 stage-A per-batch moments
//       block 274       init Z with bf1 bias; zero S/Q/ticket/flag
__global__ __launch_bounds__(256) void k_wa(const float* __restrict__ x,
                                            const float* __restrict__ Wm0,
                                            const float* __restrict__ Wdc,
                                            const float* __restrict__ bf1,
                                            float* __restrict__ ws) {
    __shared__ float L[61 * 257];   // union: fold tile 8192 / T2 512 / A red
    int blk = blockIdx.x, t = threadIdx.x;
    if (blk < 192) {
        // ---- fold V: ma0=2blk, ma1=2blk+1 ; K=256 tiled by 32 into LDS
        float* tile = L;                       // [2][32][128]
        int ma0 = 2 * blk, ma1 = ma0 + 1;
        int a0 = ma0 % 6, a1 = ma1 % 6;
        int m0 = ma0 / 6, m1 = ma1 / 6;
        int aa = __builtin_amdgcn_readfirstlane(t >> 7);   // wave-uniform
        int v = t & 127;
        const float* wm = Wm0 + (aa ? m1 : m0) * 256;      // scalar loads
        float s = 0.f;
        for (int k8 = 0; k8 < 8; ++k8) {
            int e0 = k8 * 32;
            for (int g = t; g < 8192; g += 256) {
                int gv = g & 127, e_loc = (g >> 7) & 31, ga = g >> 12;
                int rr = (e0 + e_loc) * 6 + (ga ? a1 : a0);
                tile[ga * 4096 + e_loc * 128 + gv] = Wdc[rr * 131 + 3 + gv];
            }
            __syncthreads();
            const float* tp = tile + aa * 4096 + v;
#pragma unroll
            for (int e_loc = 0; e_loc < 32; ++e_loc)
                s = fmaf(wm[e0 + e_loc], tp[e_loc * 128], s);
            __syncthreads();
        }
        ws[OFF_V + v * 384 + ma0 + aa] = s;    // transposed store
    } else if (blk < 210) {
        // ---- fold T2 for pair p=(a,j): T2[m][a*3+j] = sum_e Wm0[m,e]*col[e]
        float* col = L;                        // [256]
        float* red = L + 256;                  // [256]
        int p = blk - 192, a = p / 3, j = p % 3;
        col[t] = Wdc[(t * 6 + a) * 131 + j];   // 1 scattered load / thread
        __syncthreads();
        int m = t >> 2, q = t & 3;
        const float* wm = Wm0 + m * 256 + q * 64;
        const float* cl = col + q * 64;
        float s = 0.f;
#pragma unroll 8
        for (int i = 0; i < 64; ++i) s = fmaf(wm[i], cl[i], s);
        red[t] = s;
        __syncthreads();
        if (t < 64) {
            float v = (red[t * 4] + red[t * 4 + 1]) + (red[t * 4 + 2] + red[t * 4 + 3]);
            ws[OFF_T2 + t * 18 + a * 3 + j] = v;
        }
    } else if (blk < 274) {
        // ---- stage A
        int b = blk - 210;
        float* red = L;                        // [61][257]
        float acc[61];
#pragma unroll
        for (int i = 0; i < 61; ++i) acc[i] = 0.f;
#pragma unroll 2
        for (int k = 0; k < 8; ++k) {
            int n = t + 256 * k;
            const float* xp = x + (size_t)(b * NPTS + n) * 10;
            float xv[10];
#pragma unroll
            for (int j = 0; j < 5; ++j) {
                float2 v = *(const float2*)(xp + 2 * j);
                xv[2 * j] = v.x; xv[2 * j + 1] = v.y;
            }
            float x0 = xv[0], x1 = xv[1], x2 = xv[2];
            float rn = x0 * x0 + x1 * x1 + x2 * x2;
            float norm = sqrtf(rn);
            float inv = 1.f / (norm + 1e-8f);
            float c2[6];
            c2[0] = fmaxf(x2, 0.f) * inv; c2[1] = fmaxf(-x2, 0.f) * inv;
            c2[2] = fmaxf(x1, 0.f) * inv; c2[3] = fmaxf(-x1, 0.f) * inv;
            c2[4] = fmaxf(x0, 0.f) * inv; c2[5] = fmaxf(-x0, 0.f) * inv;
#pragma unroll
            for (int a = 0; a < 6; ++a) c2[a] *= c2[a];
            float dw = 1.f - (rn - 1.f) * (1.f / 3.f);
            if (dw < 0.f) dw = 0.f;
            if (norm <= 0.f) dw = 0.f;
            float cw[6];
#pragma unroll
            for (int a = 0; a < 6; ++a) cw[a] = c2[a] * dw;
#pragma unroll
            for (int c = 0; c < 10; ++c) {
                float dv = (c < 7) ? xv[3 + c] : xv[c - 7];
#pragma unroll
                for (int a = 0; a < 6; ++a)
                    acc[c * 6 + a] = fmaf(dv, cw[a], acc[c * 6 + a]);
            }
            acc[60] += dw;
        }
#pragma unroll
        for (int i = 0; i < 61; ++i) red[i * 257 + t] = acc[i];
        __syncthreads();
        if (t < 61) {
            float s = 0.f;
#pragma unroll 8
            for (int j = 0; j < 256; ++j) s += red[t * 257 + j];
            ws[OFF_M + b * 61 + t] = s;
        }
    } else {
        // ---- init Z with bias; zero S/Q/ticket/flag
        for (int g = t; g < 64 * 128; g += 256) ws[OFF_Z + g] = bf1[g & 127];
        ws[OFF_SQ + t] = 0.f;                  // covers S,Q,ticket,flag (256 floats)
    }
}

// ---------------------------------------------------------------------------
// k_b1z: b1 + bn2 + z fused (unchanged from round 2, proven).
__global__ __launch_bounds__(256) void k_b1z(const float* __restrict__ Wdir,
                                             const float* __restrict__ g1,
                                             const float* __restrict__ b1,
                                             const float* __restrict__ Wdir2,
                                             const float* __restrict__ g2,
                                             const float* __restrict__ b2,
                                             const float* __restrict__ Wf1,
                                             float* __restrict__ ws) {
    __shared__ float L[14496];
    float* Wd  = L;            // [64][61]; reused as D2l [64][33]
    float* D2l = L;
    float* Ml  = L + 3904;     // [64][61]; reused as wfl [128][33]
    float* wfl = L + 3904;
    float* h1  = L + 8128;     // [64][64]
    float* wt2 = L + 12224;    // [32][65]
    float* sc  = L + 14304;
    float* of  = L + 14368;
    float* scl = L + 14432;
    float* ofl = L + 14464;
    int blk = blockIdx.x, t = threadIdx.x;
    for (int g = t; g < 64 * 61; g += 256) Ml[g] = ws[OFF_M + g];
    for (int g = t; g < 3840; g += 256) Wd[(g / 60) * 61 + g % 60] = Wdir[g];
    {
        const float* src = Wdir2 + blk * 32 * 64;
        for (int g = t; g < 2048; g += 256) wt2[(g >> 6) * 65 + (g & 63)] = src[g];
    }
    __syncthreads();
    int m = t & 63;
    float Wr[60];
#pragma unroll
    for (int r = 0; r < 60; ++r) Wr[r] = Wd[m * 61 + r];
#pragma unroll
    for (int k = 0; k < 16; ++k) {
        int e0 = t + 256 * k;
        int b = e0 >> 6;
        const float* Mb = Ml + b * 61;
        float s = 0.f;
#pragma unroll
        for (int a = 0; a < 6; ++a)
#pragma unroll
            for (int c = 0; c < 10; ++c)
                s = fmaf(Wr[a * 10 + c], Mb[c * 6 + a], s);
        h1[e0] = s / Mb[60];
    }
    __syncthreads();
    if (t < 64) {
        float s = 0.f, q = 0.f;
#pragma unroll 8
        for (int b = 0; b < 64; ++b) { float v = h1[b * 64 + t]; s += v; q = fmaf(v, v, q); }
        float mean = s * (1.f / 64.f);
        float var = q * (1.f / 64.f) - mean * mean;
        float scale = g1[t] * rsqrtf(var + 1e-5f);
        sc[t] = scale; of[t] = b1[t] - mean * scale;
    }
    __syncthreads();
#pragma unroll
    for (int k = 0; k < 16; ++k) {
        int e0 = t + 256 * k;
        h1[e0] = fmaxf(fmaf(h1[e0], sc[e0 & 63], of[e0 & 63]), 0.f);
    }
    __syncthreads();
    {
        int e_loc = t & 31;
        float wr[64];
#pragma unroll
        for (int mm = 0; mm < 64; ++mm) wr[mm] = wt2[e_loc * 65 + mm];
        int b0 = t >> 5;
#pragma unroll
        for (int k = 0; k < 8; ++k) {
            int b = b0 + 8 * k;
            const float* h = h1 + b * 64;
            float s = 0.f;
#pragma unroll
            for (int mm = 0; mm < 64; ++mm) s = fmaf(h[mm], wr[mm], s);
            D2l[b * 33 + e_loc] = s;
        }
    }
    __syncthreads();
    for (int g = t; g < 128 * 32; g += 256)
        wfl[(g >> 5) * 33 + (g & 31)] = Wf1[(g >> 5) * 256 + blk * 32 + (g & 31)];
    if (t < 32) {
        float s = 0.f, q = 0.f;
#pragma unroll
        for (int b = 0; b < 64; ++b) { float v = D2l[b * 33 + t]; s += v; q = fmaf(v, v, q); }
        float mean = s * (1.f / 64.f);
        float var = q * (1.f / 64.f) - mean * mean;
        int E = blk * 32 + t;
        float scale = g2[E] * rsqrtf(var + 1e-5f);
        scl[t] = scale; ofl[t] = b2[E] - mean * scale;
    }
    __syncthreads();
    for (int g = t; g < 2048; g += 256) {
        int b = g >> 5, e = g & 31;
        D2l[b * 33 + e] = fmaxf(fmaf(D2l[b * 33 + e], scl[e], ofl[e]), 0.f);
    }
    __syncthreads();
    {
        int v = t & 127, half = t >> 7;
        float wv[32];
#pragma unroll
        for (int e = 0; e < 32; ++e) wv[e] = wfl[v * 33 + e];
#pragma unroll
        for (int j = 0; j < 32; ++j) {
            int b = half * 32 + j;
            const float* d = D2l + b * 33;
            float s = 0.f;
#pragma unroll
            for (int e = 0; e < 32; ++e) s = fmaf(d[e], wv[e], s);
            atomicAdd(&ws[OFF_Z + b * 128 + v], s);
        }
    }
}

// ---------------------------------------------------------------------------
// k_cfe: bn3 stats (atomicAdd S/Q) -> device ticket barrier -> epilogue.
// 512 blocks x 256 thr; LDS 51.7 KB, launch_bounds(256,2) => >=2 blocks/CU
// => all 512 co-resident (required for the spin barrier).
__global__ __launch_bounds__(256, 2) void k_cfe(const float* __restrict__ x,
                                                const float* __restrict__ Wcm,
                                                const float* __restrict__ bcm,
                                                const float* __restrict__ g3,
                                                const float* __restrict__ b3,
                                                const float* __restrict__ Wf2,
                                                const float* __restrict__ bf2,
                                                float* __restrict__ ws,
                                                float* __restrict__ out) {
    __shared__ __attribute__((aligned(16))) float L[12928];
    float* zl   = L;           // [128]
    float* T2l  = L + 128;     // [1152]
    float* U2l  = L + 1280;    // [384]
    float* Wl24 = L + 1664;    // [64][24] {T2 at a*4+j, U2 at a*4+3}
    float* Pl   = L + 3200;    // [64][12] {Wf2[0..6], scale@7, off@8}
    float* C2l  = L + 3968;    // [64]
    float* r2   = L + 4032;    // [512]
    float* wcm  = L + 4544;    // [64*131] (c==0 only; union with yout)
    float* yout = L + 4544;    // [1792]
    int blk = blockIdx.x, t = threadIdx.x;
    int b = blk >> 3, c = blk & 7;
    bool first = (c == 0);

    // ---- stage everything once
    if (t < 128) zl[t] = ws[OFF_Z + b * 128 + t];
    for (int g = t; g < 1152; g += 256) T2l[g] = ws[OFF_T2 + g];
    for (int g = t; g < 1152; g += 256) {
        int m = g / 18, r = g % 18, a = r / 3, j = r % 3;
        Wl24[m * 24 + a * 4 + j] = ws[OFF_T2 + g];
    }
    for (int g = t; g < 448; g += 256) {
        int m = g / 7, k = g % 7;
        Pl[m * 12 + k] = Wf2[k * 64 + m];
    }
    if (first)
        for (int g = t; g < 64 * 131; g += 256) wcm[g] = Wcm[g];
    __syncthreads();
    // ---- U2 recompute ONCE (into both U2l and Wl24 slots)
    {
        const float* Vt = ws + OFF_V;
        float s0 = 0.f;
#pragma unroll 8
        for (int v = 0; v < 128; ++v) s0 = fmaf(zl[v], Vt[v * 384 + t], s0);
        U2l[t] = s0;
        Wl24[(t / 6) * 24 + (t % 6) * 4 + 3] = s0;
        if (t < 128) {
            int ma = 256 + t;
            float s1 = 0.f;
#pragma unroll 8
            for (int v = 0; v < 128; ++v) s1 = fmaf(zl[v], Vt[v * 384 + ma], s1);
            U2l[ma] = s1;
            Wl24[(ma / 6) * 24 + (ma % 6) * 4 + 3] = s1;
        }
    }
    // ---- C2 (c==0 blocks only), same order as before
    float c2v = 0.f;
    bool has0 = first && (t < 64);
    if (has0) {
        const float* w = wcm + t * 131;
        float s = bcm[t];
#pragma unroll 8
        for (int i = 0; i < 128; ++i) s = fmaf(zl[i], w[i], s);
        s = fmaf(x[(size_t)b * NPTS * 10 + 0], w[128], s);
        s = fmaf(x[(size_t)b * NPTS * 10 + 1], w[129], s);
        s = fmaf(x[(size_t)b * NPTS * 10 + 2], w[130], s);
        c2v = s;
        C2l[t] = s;
    }
    __syncthreads();

    // ---- phase C: bn3 partials (lane=m, wave g owns 64 points)
    {
        int m = t & 63;
        int g = __builtin_amdgcn_readfirstlane(t >> 6);
        float T[18], U[6];
#pragma unroll
        for (int r = 0; r < 18; ++r) T[r] = T2l[m * 18 + r];
#pragma unroll
        for (int a = 0; a < 6; ++a) U[a] = U2l[m * 6 + a];
        float accS = 0.f, accQ = 0.f;
        int p0 = c * 256 + g * 64;
        const float* xb = x + (size_t)b * NPTS * 10;
#pragma unroll 4
        for (int i = 0; i < 64; ++i) {
            const float* xp = xb + (p0 + i) * 10;     // wave-uniform address
            float x0 = xp[0], x1 = xp[1], x2 = xp[2];
            float rn = x0 * x0 + x1 * x1 + x2 * x2;
            float inv = 1.f / (sqrtf(rn) + 1e-8f);
            float c2[6];
            c2[0] = fmaxf(x2, 0.f) * inv; c2[1] = fmaxf(-x2, 0.f) * inv;
            c2[2] = fmaxf(x1, 0.f) * inv; c2[3] = fmaxf(-x1, 0.f) * inv;
            c2[4] = fmaxf(x0, 0.f) * inv; c2[5] = fmaxf(-x0, 0.f) * inv;
            float h = 0.f;
#pragma unroll
            for (int a = 0; a < 6; ++a) {
                float cc = c2[a] * c2[a];
                float ta = fmaf(x0, T[a * 3], fmaf(x1, T[a * 3 + 1], fmaf(x2, T[a * 3 + 2], U[a])));
                h = fmaf(cc, ta, h);
            }
            if (has0 && i == 0) h = c2v;              // g==0 implied by t<64
            accS += h;
            accQ = fmaf(h, h, accQ);
        }
        r2[t] = accS; r2[256 + t] = accQ;
    }
    __syncthreads();
    if (t < 64) {
        atomicAdd(&ws[OFF_SQ + t], r2[t] + r2[64 + t] + r2[128 + t] + r2[192 + t]);
    } else if (t < 128) {
        int mm = t - 64;
        atomicAdd(&ws[OFF_SQ + 64 + mm], r2[256 + mm] + r2[320 + mm] + r2[384 + mm] + r2[448 + mm]);
    }
    __syncthreads();
    __threadfence();
    // ---- device-scope ticket barrier (all 512 blocks co-resident)
    {
        int* ticket = (int*)(ws + OFF_SQ + 128);
        int* flag   = (int*)(ws + OFF_SQ + 192);
        if (t == 0) {
            int old = __hip_atomic_fetch_add(ticket, 1, __ATOMIC_ACQ_REL, __HIP_MEMORY_SCOPE_AGENT);
            if (old == 511) {
                __hip_atomic_store(flag, 1, __ATOMIC_RELEASE, __HIP_MEMORY_SCOPE_AGENT);
            } else {
                while (__hip_atomic_load(flag, __ATOMIC_ACQUIRE, __HIP_MEMORY_SCOPE_AGENT) == 0)
                    __builtin_amdgcn_s_sleep(16);
            }
        }
        __syncthreads();
    }
    // ---- every block computes bn3 scale/off from the global S/Q (identical FP)
    if (t < 64) {
        float S = __hip_atomic_load(&ws[OFF_SQ + t], __ATOMIC_RELAXED, __HIP_MEMORY_SCOPE_AGENT);
        float Q = __hip_atomic_load(&ws[OFF_SQ + 64 + t], __ATOMIC_RELAXED, __HIP_MEMORY_SCOPE_AGENT);
        float mean = S * (1.f / 131072.f);
        float var = Q * (1.f / 131072.f) - mean * mean;
        float scale = g3[t] * rsqrtf(var + 1e-5f);
        Pl[t * 12 + 7] = scale;
        Pl[t * 12 + 8] = b3[t] - mean * scale;
    }
    __syncthreads();

    // ---- phase E: epilogue (thread = point), coalesced out
    {
        int idx = blk * 256 + t;
        const float* xp = x + (size_t)idx * 10;
        float x0 = xp[0], x1 = xp[1], x2 = xp[2];
        float rn = x0 * x0 + x1 * x1 + x2 * x2;
        float inv = 1.f / (sqrtf(rn) + 1e-8f);
        float c2[6];
        c2[0] = fmaxf(x2, 0.f) * inv; c2[1] = fmaxf(-x2, 0.f) * inv;
        c2[2] = fmaxf(x1, 0.f) * inv; c2[3] = fmaxf(-x1, 0.f) * inv;
        c2[4] = fmaxf(x0, 0.f) * inv; c2[5] = fmaxf(-x0, 0.f) * inv;
#pragma unroll
        for (int a = 0; a < 6; ++a) c2[a] *= c2[a];
        bool c0 = ((idx & 2047) == 0);
        float y[7];
#pragma unroll
        for (int k = 0; k < 7; ++k) y[k] = bf2[k];
#pragma unroll 4
        for (int m = 0; m < 64; ++m) {
            const float4* Wm = (const float4*)(Wl24 + m * 24);
            float h = 0.f;
#pragma unroll
            for (int a = 0; a < 6; ++a) {
                float4 wq = Wm[a];   // {T0,T1,T2,U}
                float ta = fmaf(x0, wq.x, fmaf(x1, wq.y, fmaf(x2, wq.z, wq.w)));
                h = fmaf(c2[a], ta, h);
            }
            if (c0) h = C2l[m];
            const float4* Pm = (const float4*)(Pl + m * 12);
            float4 p0 = Pm[0], p1 = Pm[1];
            float offv = Pl[m * 12 + 8];
            float r = fmaxf(fmaf(h, p1.w, offv), 0.f);
            y[0] = fmaf(r, p0.x, y[0]); y[1] = fmaf(r, p0.y, y[1]);
            y[2] = fmaf(r, p0.z, y[2]); y[3] = fmaf(r, p0.w, y[3]);
            y[4] = fmaf(r, p1.x, y[4]); y[5] = fmaf(r, p1.y, y[5]);
            y[6] = fmaf(r, p1.z, y[6]);
        }
#pragma unroll
        for (int k = 0; k < 7; ++k) yout[t * 7 + k] = 1.f / (1.f + __expf(-y[k]));
        __syncthreads();
        float* op = out + (size_t)blk * 1792;
        for (int g = t; g < 1792; g += 256) op[g] = yout[g];
    }
}

// ---------------------------------------------------------------------------
extern "C" void kernel_launch(void* const* d_in, const int* in_sizes, int n_in,
                              void* d_out, int out_size, void* d_ws, size_t ws_size,
                              hipStream_t stream) {
    const float* x     = (const float*)d_in[0];
    // d_in[1]=Wc, d_in[2]=bc : dead code in reference
    const float* Wdir  = (const float*)d_in[3];
    const float* g1    = (const float*)d_in[4];
    const float* b1    = (const float*)d_in[5];
    const float* Wdir2 = (const float*)d_in[6];
    const float* g2    = (const float*)d_in[7];
    const float* b2    = (const float*)d_in[8];
    const float* Wf1   = (const float*)d_in[9];
    const float* bf1   = (const float*)d_in[10];
    const float* Wcm   = (const float*)d_in[11];
    const float* bcm   = (const float*)d_in[12];
    const float* Wdc   = (const float*)d_in[13];
    const float* Wm0   = (const float*)d_in[14];
    const float* g3    = (const float*)d_in[15];
    const float* b3    = (const float*)d_in[16];
    const float* Wf2   = (const float*)d_in[17];
    const float* bf2   = (const float*)d_in[18];
    float* ws  = (float*)d_ws;
    float* out = (float*)d_out;

    k_wa <<<275, 256, 0, stream>>>(x, Wm0, Wdc, bf1, ws);
    k_b1z<<<8,   256, 0, stream>>>(Wdir, g1, b1, Wdir2, g2, b2, Wf1, ws);
    k_cfe<<<512, 256, 0, stream>>>(x, Wcm, bcm, g3, b3, Wf2, bf2, ws, out);
}

// Round 4
// 227.274 us; speedup vs baseline: 1.1214x; 1.1214x over previous
//
#include <hip/hip_runtime.h>
#include <math.h>

// Problem constants
#define BATCH 64
#define NPTS  2048
// ws float offsets (footprint unchanged: 176256 floats)
#define OFF_H0  0        // [64][64] raw h of point 0 (reuses dead M region)
#define OFF_M   0        // [64][61] M[b][c*6+a], Sdw at [b][60] (dead after k_b1z)
#define OFF_T2  4096     // [64][18]  T2[m][a*3+j]
#define OFF_V   8192     // TRANSPOSED: Vt[v][ma] = [128][384]
#define OFF_Z   73728    // [64][128] z (bias-init + atomic partials)
#define OFF_C2  81920    // [64][64]  center2[b][m] (written by k_fin)
#define OFF_U2  86016    // [64][384] U2[b][ma] (written by k_c c==0 blocks)
#define OFF_GP  110592   // [512][128] per-block bn3 partials
#define OFF_SO  176128   // [128] scale[64], offset[64]

// ---------------------------------------------------------------------------
// k_wa: blocks 0..23   fold-V as tiled GEMM (a, v-quarter); Wdc read once
//       blocks 24..41  fold-T2 (one (a,j) pair per block)
//       blocks 42..105 stage-A per-batch moments
//       block 106      init Z with bf1 bias
__global__ __launch_bounds__(256) void k_wa(const float* __restrict__ x,
                                            const float* __restrict__ Wm0,
                                            const float* __restrict__ Wdc,
                                            const float* __restrict__ bf1,
                                            float* __restrict__ ws) {
    __shared__ __attribute__((aligned(16))) float L[61 * 257];
    int blk = blockIdx.x, t = threadIdx.x;
    if (blk < 24) {
        // ---- fold V: C[m,a,v] = sum_e Wm0[m,e] * Wdc[e*6+a][3+v]
        // block = (a, vq); per-thread (m, vg) owns 8 v outputs; e tiled by 32.
        float* wml = L;            // [64][33]
        float* pl  = L + 2112;     // [32][36] (36: float4-aligned rows)
        int a = blk >> 2, vq = blk & 3;
        int m = t & 63, vg = t >> 6;           // vg 0..3 (wave-uniform)
        float acc[8];
#pragma unroll
        for (int i = 0; i < 8; ++i) acc[i] = 0.f;
        for (int e0 = 0; e0 < 256; e0 += 32) {
            for (int g = t; g < 2048; g += 256)
                wml[(g >> 5) * 33 + (g & 31)] = Wm0[(g >> 5) * 256 + e0 + (g & 31)];
            for (int g = t; g < 1024; g += 256)
                pl[(g >> 5) * 36 + (g & 31)] =
                    Wdc[((e0 + (g >> 5)) * 6 + a) * 131 + 3 + vq * 32 + (g & 31)];
            __syncthreads();
#pragma unroll
            for (int e = 0; e < 32; ++e) {
                float wv = wml[m * 33 + e];
                const float4* p4 = (const float4*)(pl + e * 36 + vg * 8);
                float4 pa = p4[0], pb = p4[1];
                acc[0] = fmaf(wv, pa.x, acc[0]); acc[1] = fmaf(wv, pa.y, acc[1]);
                acc[2] = fmaf(wv, pa.z, acc[2]); acc[3] = fmaf(wv, pa.w, acc[3]);
                acc[4] = fmaf(wv, pb.x, acc[4]); acc[5] = fmaf(wv, pb.y, acc[5]);
                acc[6] = fmaf(wv, pb.z, acc[6]); acc[7] = fmaf(wv, pb.w, acc[7]);
            }
            __syncthreads();
        }
#pragma unroll
        for (int vv = 0; vv < 8; ++vv)
            ws[OFF_V + (vq * 32 + vg * 8 + vv) * 384 + m * 6 + a] = acc[vv];
    } else if (blk < 42) {
        // ---- fold T2 for pair p=(a,j)
        float* col = L;
        float* red = L + 256;
        int p = blk - 24, a = p / 3, j = p % 3;
        col[t] = Wdc[(t * 6 + a) * 131 + j];
        __syncthreads();
        int m = t >> 2, q = t & 3;
        const float* wm = Wm0 + m * 256 + q * 64;
        const float* cl = col + q * 64;
        float s = 0.f;
#pragma unroll 8
        for (int i = 0; i < 64; ++i) s = fmaf(wm[i], cl[i], s);
        red[t] = s;
        __syncthreads();
        if (t < 64) {
            float v = (red[t * 4] + red[t * 4 + 1]) + (red[t * 4 + 2] + red[t * 4 + 3]);
            ws[OFF_T2 + t * 18 + a * 3 + j] = v;
        }
    } else if (blk < 106) {
        // ---- stage A
        int b = blk - 42;
        float* red = L;                        // [61][257]
        float acc[61];
#pragma unroll
        for (int i = 0; i < 61; ++i) acc[i] = 0.f;
#pragma unroll 2
        for (int k = 0; k < 8; ++k) {
            int n = t + 256 * k;
            const float* xp = x + (size_t)(b * NPTS + n) * 10;
            float xv[10];
#pragma unroll
            for (int j = 0; j < 5; ++j) {
                float2 v = *(const float2*)(xp + 2 * j);
                xv[2 * j] = v.x; xv[2 * j + 1] = v.y;
            }
            float x0 = xv[0], x1 = xv[1], x2 = xv[2];
            float rn = x0 * x0 + x1 * x1 + x2 * x2;
            float norm = sqrtf(rn);
            float inv = 1.f / (norm + 1e-8f);
            float c2[6];
            c2[0] = fmaxf(x2, 0.f) * inv; c2[1] = fmaxf(-x2, 0.f) * inv;
            c2[2] = fmaxf(x1, 0.f) * inv; c2[3] = fmaxf(-x1, 0.f) * inv;
            c2[4] = fmaxf(x0, 0.f) * inv; c2[5] = fmaxf(-x0, 0.f) * inv;
#pragma unroll
            for (int a = 0; a < 6; ++a) c2[a] *= c2[a];
            float dw = 1.f - (rn - 1.f) * (1.f / 3.f);
            if (dw < 0.f) dw = 0.f;
            if (norm <= 0.f) dw = 0.f;
            float cw[6];
#pragma unroll
            for (int a = 0; a < 6; ++a) cw[a] = c2[a] * dw;
#pragma unroll
            for (int c = 0; c < 10; ++c) {
                float dv = (c < 7) ? xv[3 + c] : xv[c - 7];
#pragma unroll
                for (int a = 0; a < 6; ++a)
                    acc[c * 6 + a] = fmaf(dv, cw[a], acc[c * 6 + a]);
            }
            acc[60] += dw;
        }
#pragma unroll
        for (int i = 0; i < 61; ++i) red[i * 257 + t] = acc[i];
        __syncthreads();
        if (t < 61) {
            float s = 0.f;
#pragma unroll 8
            for (int j = 0; j < 256; ++j) s += red[t * 257 + j];
            ws[OFF_M + b * 61 + t] = s;
        }
    } else {
        for (int g = t; g < 64 * 128; g += 256) ws[OFF_Z + g] = bf1[g & 127];
    }
}

// ---------------------------------------------------------------------------
// k_b1z: unchanged (proven in round 2).
__global__ __launch_bounds__(256) void k_b1z(const float* __restrict__ Wdir,
                                             const float* __restrict__ g1,
                                             const float* __restrict__ b1,
                                             const float* __restrict__ Wdir2,
                                             const float* __restrict__ g2,
                                             const float* __restrict__ b2,
                                             const float* __restrict__ Wf1,
                                             float* __restrict__ ws) {
    __shared__ float L[14496];
    float* Wd  = L;
    float* D2l = L;
    float* Ml  = L + 3904;
    float* wfl = L + 3904;
    float* h1  = L + 8128;
    float* wt2 = L + 12224;
    float* sc  = L + 14304;
    float* of  = L + 14368;
    float* scl = L + 14432;
    float* ofl = L + 14464;
    int blk = blockIdx.x, t = threadIdx.x;
    for (int g = t; g < 64 * 61; g += 256) Ml[g] = ws[OFF_M + g];
    for (int g = t; g < 3840; g += 256) Wd[(g / 60) * 61 + g % 60] = Wdir[g];
    {
        const float* src = Wdir2 + blk * 32 * 64;
        for (int g = t; g < 2048; g += 256) wt2[(g >> 6) * 65 + (g & 63)] = src[g];
    }
    __syncthreads();
    int m = t & 63;
    float Wr[60];
#pragma unroll
    for (int r = 0; r < 60; ++r) Wr[r] = Wd[m * 61 + r];
#pragma unroll
    for (int k = 0; k < 16; ++k) {
        int e0 = t + 256 * k;
        int b = e0 >> 6;
        const float* Mb = Ml + b * 61;
        float s = 0.f;
#pragma unroll
        for (int a = 0; a < 6; ++a)
#pragma unroll
            for (int c = 0; c < 10; ++c)
                s = fmaf(Wr[a * 10 + c], Mb[c * 6 + a], s);
        h1[e0] = s / Mb[60];
    }
    __syncthreads();
    if (t < 64) {
        float s = 0.f, q = 0.f;
#pragma unroll 8
        for (int b = 0; b < 64; ++b) { float v = h1[b * 64 + t]; s += v; q = fmaf(v, v, q); }
        float mean = s * (1.f / 64.f);
        float var = q * (1.f / 64.f) - mean * mean;
        float scale = g1[t] * rsqrtf(var + 1e-5f);
        sc[t] = scale; of[t] = b1[t] - mean * scale;
    }
    __syncthreads();
#pragma unroll
    for (int k = 0; k < 16; ++k) {
        int e0 = t + 256 * k;
        h1[e0] = fmaxf(fmaf(h1[e0], sc[e0 & 63], of[e0 & 63]), 0.f);
    }
    __syncthreads();
    {
        int e_loc = t & 31;
        float wr[64];
#pragma unroll
        for (int mm = 0; mm < 64; ++mm) wr[mm] = wt2[e_loc * 65 + mm];
        int b0 = t >> 5;
#pragma unroll
        for (int k = 0; k < 8; ++k) {
            int b = b0 + 8 * k;
            const float* h = h1 + b * 64;
            float s = 0.f;
#pragma unroll
            for (int mm = 0; mm < 64; ++mm) s = fmaf(h[mm], wr[mm], s);
            D2l[b * 33 + e_loc] = s;
        }
    }
    __syncthreads();
    for (int g = t; g < 128 * 32; g += 256)
        wfl[(g >> 5) * 33 + (g & 31)] = Wf1[(g >> 5) * 256 + blk * 32 + (g & 31)];
    if (t < 32) {
        float s = 0.f, q = 0.f;
#pragma unroll
        for (int b = 0; b < 64; ++b) { float v = D2l[b * 33 + t]; s += v; q = fmaf(v, v, q); }
        float mean = s * (1.f / 64.f);
        float var = q * (1.f / 64.f) - mean * mean;
        int E = blk * 32 + t;
        float scale = g2[E] * rsqrtf(var + 1e-5f);
        scl[t] = scale; ofl[t] = b2[E] - mean * scale;
    }
    __syncthreads();
    for (int g = t; g < 2048; g += 256) {
        int b = g >> 5, e = g & 31;
        D2l[b * 33 + e] = fmaxf(fmaf(D2l[b * 33 + e], scl[e], ofl[e]), 0.f);
    }
    __syncthreads();
    {
        int v = t & 127, half = t >> 7;
        float wv[32];
#pragma unroll
        for (int e = 0; e < 32; ++e) wv[e] = wfl[v * 33 + e];
#pragma unroll
        for (int j = 0; j < 32; ++j) {
            int b = half * 32 + j;
            const float* d = D2l + b * 33;
            float s = 0.f;
#pragma unroll
            for (int e = 0; e < 32; ++e) s = fmaf(d[e], wv[e], s);
            atomicAdd(&ws[OFF_Z + b * 128 + v], s);
        }
    }
}

// ---------------------------------------------------------------------------
// k_c: bn3 partials. 512 blocks x 512 threads (8 waves -> 4 waves/SIMD TLP).
// x slice LDS-staged (kills serial s_load chain). Raw stats only; point-0
// h recorded to ws[OFF_H0]; correction happens in k_fin. c==0 blocks also
// persist U2[b] to ws for k_e.
__global__ __launch_bounds__(512) void k_c(const float* __restrict__ x,
                                           float* __restrict__ ws) {
    __shared__ float L[3712];
    float* xl  = L;            // [256][4] xyz of this block's points
    float* zl  = L + 1024;     // [128]
    float* T2l = L + 1152;     // [1152]
    float* U2l = L + 2304;     // [384]
    float* r2  = L + 2688;     // [1024]
    int blk = blockIdx.x, t = threadIdx.x;
    int b = blk >> 3, c = blk & 7;
    const float* xb = x + (size_t)b * NPTS * 10;
    if (t < 256) {
        const float* xp = xb + (size_t)(c * 256 + t) * 10;
        float2 v01 = *(const float2*)xp;
        xl[t * 4 + 0] = v01.x; xl[t * 4 + 1] = v01.y; xl[t * 4 + 2] = xp[2];
    }
    if (t < 128) zl[t] = ws[OFF_Z + b * 128 + t];
    for (int g = t; g < 1152; g += 512) T2l[g] = ws[OFF_T2 + g];
    __syncthreads();
    // U2[ma] = sum_v z[v] * Vt[v][ma] ; coalesced across ma
    if (t < 384) {
        const float* Vt = ws + OFF_V;
        float s0 = 0.f;
#pragma unroll 8
        for (int v = 0; v < 128; ++v) s0 = fmaf(zl[v], Vt[v * 384 + t], s0);
        U2l[t] = s0;
        if (c == 0) ws[OFF_U2 + b * 384 + t] = s0;
    }
    __syncthreads();
    int m = t & 63;
    int g = __builtin_amdgcn_readfirstlane(t >> 6);   // wave 0..7
    float T[18], U[6];
#pragma unroll
    for (int r = 0; r < 18; ++r) T[r] = T2l[m * 18 + r];
#pragma unroll
    for (int a = 0; a < 6; ++a) U[a] = U2l[m * 6 + a];
    float accS = 0.f, accQ = 0.f;
    const float* xw = xl + g * 32 * 4;                // wave's 32 points
#pragma unroll 4
    for (int i = 0; i < 32; ++i) {
        float x0 = xw[i * 4], x1 = xw[i * 4 + 1], x2 = xw[i * 4 + 2];
        float rn = x0 * x0 + x1 * x1 + x2 * x2;
        float inv = 1.f / (sqrtf(rn) + 1e-8f);
        float c2[6];
        c2[0] = fmaxf(x2, 0.f) * inv; c2[1] = fmaxf(-x2, 0.f) * inv;
        c2[2] = fmaxf(x1, 0.f) * inv; c2[3] = fmaxf(-x1, 0.f) * inv;
        c2[4] = fmaxf(x0, 0.f) * inv; c2[5] = fmaxf(-x0, 0.f) * inv;
        float h = 0.f;
#pragma unroll
        for (int a = 0; a < 6; ++a) {
            float cc = c2[a] * c2[a];
            float ta = fmaf(x0, T[a * 3], fmaf(x1, T[a * 3 + 1], fmaf(x2, T[a * 3 + 2], U[a])));
            h = fmaf(cc, ta, h);
        }
        if (c == 0 && g == 0 && i == 0)
            ws[OFF_H0 + b * 64 + m] = h;              // raw h of point 0
        accS += h;
        accQ = fmaf(h, h, accQ);
    }
    r2[t] = accS; r2[512 + t] = accQ;
    __syncthreads();
    if (t < 64) {
        float s = 0.f;
#pragma unroll
        for (int gg = 0; gg < 8; ++gg) s += r2[gg * 64 + t];
        ws[OFF_GP + blk * 128 + t] = s;
    } else if (t < 128) {
        int mm = t - 64;
        float q = 0.f;
#pragma unroll
        for (int gg = 0; gg < 8; ++gg) q += r2[512 + gg * 64 + mm];
        ws[OFF_GP + blk * 128 + t] = q;
    }
}

// ---------------------------------------------------------------------------
// k_fin: GP reduce + C2 compute + point-0 correction -> bn3 scale/off + C2.
__global__ __launch_bounds__(256) void k_fin(const float* __restrict__ x,
                                             const float* __restrict__ Wcm,
                                             const float* __restrict__ bcm,
                                             const float* __restrict__ g3,
                                             const float* __restrict__ b3,
                                             float* __restrict__ ws) {
    __shared__ float L[13824];
    float* zl = L;             // [64][128]  (reads are wave-uniform -> no pad)
    float* wl = L + 8192;      // [64][69]   Wcm half-tile, padded
    float* xl = L + 12608;     // [192] xyz0 per batch
    float* cp = L + 12800;     // [8][64]: cs partials then cq partials
    float* r  = L + 13312;     // [512]
    int t = threadIdx.x;
    for (int g = t; g < 8192; g += 256) zl[g] = ws[OFF_Z + g];
    if (t < 192) xl[t] = x[(size_t)(t / 3) * NPTS * 10 + t % 3];
    for (int g = t; g < 64 * 68; g += 256) wl[(g / 68) * 69 + g % 68] = Wcm[(g / 68) * 131 + g % 68];
    __syncthreads();
    int m = t & 63, bq = t >> 6;
    float acc[16];
#pragma unroll
    for (int k = 0; k < 16; ++k) {
        int b = bq * 16 + k;
        float s = bcm[m];
        const float* z = zl + b * 128;                // wave-uniform
        const float* w = wl + m * 69;
#pragma unroll 4
        for (int i = 0; i < 68; ++i) s = fmaf(z[i], w[i], s);
        acc[k] = s;
    }
    __syncthreads();
    for (int g = t; g < 64 * 63; g += 256) wl[(g / 63) * 69 + g % 63] = Wcm[(g / 63) * 131 + 68 + g % 63];
    __syncthreads();
    float cs = 0.f, cq = 0.f;
#pragma unroll
    for (int k = 0; k < 16; ++k) {
        int b = bq * 16 + k;
        float s = acc[k];
        const float* z = zl + b * 128 + 68;
        const float* w = wl + m * 69;
#pragma unroll 4
        for (int i = 0; i < 60; ++i) s = fmaf(z[i], w[i], s);
        s = fmaf(xl[b * 3 + 0], w[60], s);
        s = fmaf(xl[b * 3 + 1], w[61], s);
        s = fmaf(xl[b * 3 + 2], w[62], s);
        ws[OFF_C2 + b * 64 + m] = s;
        cs += s;
        cq = fmaf(s, s, cq);
    }
    cp[bq * 64 + m] = cs;
    cp[256 + bq * 64 + m] = cq;
    // GP reduce (same as round 2)
    {
        int q = t >> 6;
        float s = 0.f, qq = 0.f;
#pragma unroll 8
        for (int j = 0; j < 128; ++j) {
            int blk = q * 128 + j;
            s += ws[OFF_GP + blk * 128 + m];
            qq += ws[OFF_GP + blk * 128 + 64 + m];
        }
        r[t] = s; r[256 + t] = qq;
    }
    __syncthreads();
    if (t < 64) {
        float S = r[t] + r[64 + t] + r[128 + t] + r[192 + t];
        float Q = r[256 + t] + r[320 + t] + r[384 + t] + r[448 + t];
        float CS = cp[t] + cp[64 + t] + cp[128 + t] + cp[192 + t];
        float CQ = cp[256 + t] + cp[320 + t] + cp[384 + t] + cp[448 + t];
        float hs = 0.f, hq = 0.f;
#pragma unroll 8
        for (int b = 0; b < 64; ++b) {
            float v = ws[OFF_H0 + b * 64 + t];
            hs += v; hq = fmaf(v, v, hq);
        }
        S += CS - hs;
        Q += CQ - hq;
        float mean = S * (1.f / 131072.f);
        float var = Q * (1.f / 131072.f) - mean * mean;
        float scale = g3[t] * rsqrtf(var + 1e-5f);
        ws[OFF_SO + t] = scale;
        ws[OFF_SO + 64 + t] = b3[t] - mean * scale;
    }
}

// ---------------------------------------------------------------------------
// k_e: epilogue. 512 blocks x 512 threads; 2 threads per point (m-split 32+32)
// -> 4 waves/SIMD TLP, half the serial m-loop. U2/C2 read from ws.
__global__ __launch_bounds__(512) void k_e(const float* __restrict__ x,
                                           const float* __restrict__ Wf2,
                                           const float* __restrict__ bf2,
                                           const float* __restrict__ ws,
                                           float* __restrict__ out) {
    __shared__ __attribute__((aligned(16))) float L[6464];
    float* Wl24 = L;           // [64][24]: {T2 at a*4+j, U2 at a*4+3}
    float* Pl   = L + 1536;    // [64][12]: {Wf2[0..6], scale@7, off@8}
    float* C2l  = L + 2304;    // [64]
    float* yp   = L + 2368;    // [256][16]: partial y, two halves
    int blk = blockIdx.x, t = threadIdx.x;
    int b = blk >> 3;
    for (int g = t; g < 1152; g += 512) {
        int m = g / 18, r = g % 18, a = r / 3, j = r % 3;
        Wl24[m * 24 + a * 4 + j] = ws[OFF_T2 + g];
    }
    if (t < 384)
        Wl24[(t / 6) * 24 + (t % 6) * 4 + 3] = ws[OFF_U2 + b * 384 + t];
    if (t < 448) {
        int m = t / 7, k = t % 7;
        Pl[m * 12 + k] = Wf2[k * 64 + m];
    }
    if (t < 64) {
        Pl[t * 12 + 7] = ws[OFF_SO + t];
        Pl[t * 12 + 8] = ws[OFF_SO + 64 + t];
    }
    if ((blk & 7) == 0 && t < 64) C2l[t] = ws[OFF_C2 + b * 64 + t];
    __syncthreads();

    int p_loc = t >> 1, mh = t & 1;
    int p = blk * 256 + p_loc;
    const float* xp = x + (size_t)p * 10;
    float x0 = xp[0], x1 = xp[1], x2 = xp[2];
    float rn = x0 * x0 + x1 * x1 + x2 * x2;
    float inv = 1.f / (sqrtf(rn) + 1e-8f);
    float c2[6];
    c2[0] = fmaxf(x2, 0.f) * inv; c2[1] = fmaxf(-x2, 0.f) * inv;
    c2[2] = fmaxf(x1, 0.f) * inv; c2[3] = fmaxf(-x1, 0.f) * inv;
    c2[4] = fmaxf(x0, 0.f) * inv; c2[5] = fmaxf(-x0, 0.f) * inv;
#pragma unroll
    for (int a = 0; a < 6; ++a) c2[a] *= c2[a];
    bool c0 = ((p & 2047) == 0);
    float y[7];
#pragma unroll
    for (int k = 0; k < 7; ++k) y[k] = mh ? 0.f : bf2[k];
    int m0 = mh * 32;
#pragma unroll 4
    for (int mm = 0; mm < 32; ++mm) {
        int m = m0 + mm;
        const float4* Wm = (const float4*)(Wl24 + m * 24);
        float h = 0.f;
#pragma unroll
        for (int a = 0; a < 6; ++a) {
            float4 wq = Wm[a];   // {T0,T1,T2,U}
            float ta = fmaf(x0, wq.x, fmaf(x1, wq.y, fmaf(x2, wq.z, wq.w)));
            h = fmaf(c2[a], ta, h);
        }
        if (c0) h = C2l[m];
        const float4* Pm = (const float4*)(Pl + m * 12);
        float4 p0 = Pm[0], p1 = Pm[1];
        float offv = Pl[m * 12 + 8];
        float r = fmaxf(fmaf(h, p1.w, offv), 0.f);
        y[0] = fmaf(r, p0.x, y[0]); y[1] = fmaf(r, p0.y, y[1]);
        y[2] = fmaf(r, p0.z, y[2]); y[3] = fmaf(r, p0.w, y[3]);
        y[4] = fmaf(r, p1.x, y[4]); y[5] = fmaf(r, p1.y, y[5]);
        y[6] = fmaf(r, p1.z, y[6]);
    }
#pragma unroll
    for (int k = 0; k < 7; ++k) yp[p_loc * 16 + mh * 8 + k] = y[k];
    __syncthreads();
    float* op = out + (size_t)blk * 1792;
    for (int g = t; g < 1792; g += 512) {
        int pp = g / 7, k = g % 7;
        float v = yp[pp * 16 + k] + yp[pp * 16 + 8 + k];
        op[g] = 1.f / (1.f + __expf(-v));
    }
}

// ---------------------------------------------------------------------------
extern "C" void kernel_launch(void* const* d_in, const int* in_sizes, int n_in,
                              void* d_out, int out_size, void* d_ws, size_t ws_size,
                              hipStream_t stream) {
    const float* x     = (const float*)d_in[0];
    // d_in[1]=Wc, d_in[2]=bc : dead code in reference
    const float* Wdir  = (const float*)d_in[3];
    const float* g1    = (const float*)d_in[4];
    const float* b1    = (const float*)d_in[5];
    const float* Wdir2 = (const float*)d_in[6];
    const float* g2    = (const float*)d_in[7];
    const float* b2    = (const float*)d_in[8];
    const float* Wf1   = (const float*)d_in[9];
    const float* bf1   = (const float*)d_in[10];
    const float* Wcm   = (const float*)d_in[11];
    const float* bcm   = (const float*)d_in[12];
    const float* Wdc   = (const float*)d_in[13];
    const float* Wm0   = (const float*)d_in[14];
    const float* g3    = (const float*)d_in[15];
    const float* b3    = (const float*)d_in[16];
    const float* Wf2   = (const float*)d_in[17];
    const float* bf2   = (const float*)d_in[18];
    float* ws  = (float*)d_ws;
    float* out = (float*)d_out;

    k_wa <<<107, 256, 0, stream>>>(x, Wm0, Wdc, bf1, ws);
    k_b1z<<<8,   256, 0, stream>>>(Wdir, g1, b1, Wdir2, g2, b2, Wf1, ws);
    k_c  <<<512, 512, 0, stream>>>(x, ws);
    k_fin<<<1,   256, 0, stream>>>(x, Wcm, bcm, g3, b3, ws);
    k_e  <<<512, 512, 0, stream>>>(x, Wf2, bf2, ws, out);
}

// Round 5
// 202.554 us; speedup vs baseline: 1.2583x; 1.1220x over previous
//
#include <hip/hip_runtime.h>
#include <math.h>

// Problem constants
#define BATCH 64
#define NPTS  2048
// ws float offsets (footprint unchanged: 176256 floats)
#define OFF_H0  0        // [64][64] raw h of point 0 (reuses dead M region)
#define OFF_M   0        // [64][61] M[b][c*6+a], Sdw at [b][60] (dead after k_b1z)
#define OFF_T2  4096     // [64][18]  T2[m][a*3+j]  (1152 used)
#define OFF_GP2 5248     // [20][128] second-level bn3 partials (fits before OFF_V)
#define OFF_V   8192     // TRANSPOSED: Vt[v][ma] = [128][384]
#define OFF_Z   73728    // [64][128] z (bias-init + atomic partials)
#define OFF_C2  81920    // [64][64]  center2[b][m] (written by k_r)
#define OFF_U2  86016    // [64][384] U2[b][ma] (written by k_c c==0 blocks)
#define OFF_GP  110592   // [512][128] per-block bn3 partials

// ---------------------------------------------------------------------------
// k_wa: blocks 0..23   fold-V as tiled GEMM (a, v-quarter); Wdc read once
//       blocks 24..41  fold-T2 (one (a,j) pair per block)
//       blocks 42..105 stage-A per-batch moments
//       block 106      init Z with bf1 bias
__global__ __launch_bounds__(256) void k_wa(const float* __restrict__ x,
                                            const float* __restrict__ Wm0,
                                            const float* __restrict__ Wdc,
                                            const float* __restrict__ bf1,
                                            float* __restrict__ ws) {
    __shared__ __attribute__((aligned(16))) float L[61 * 257];
    int blk = blockIdx.x, t = threadIdx.x;
    if (blk < 24) {
        float* wml = L;            // [64][33]
        float* pl  = L + 2112;     // [32][36]
        int a = blk >> 2, vq = blk & 3;
        int m = t & 63, vg = t >> 6;
        float acc[8];
#pragma unroll
        for (int i = 0; i < 8; ++i) acc[i] = 0.f;
        for (int e0 = 0; e0 < 256; e0 += 32) {
            for (int g = t; g < 2048; g += 256)
                wml[(g >> 5) * 33 + (g & 31)] = Wm0[(g >> 5) * 256 + e0 + (g & 31)];
            for (int g = t; g < 1024; g += 256)
                pl[(g >> 5) * 36 + (g & 31)] =
                    Wdc[((e0 + (g >> 5)) * 6 + a) * 131 + 3 + vq * 32 + (g & 31)];
            __syncthreads();
#pragma unroll
            for (int e = 0; e < 32; ++e) {
                float wv = wml[m * 33 + e];
                const float4* p4 = (const float4*)(pl + e * 36 + vg * 8);
                float4 pa = p4[0], pb = p4[1];
                acc[0] = fmaf(wv, pa.x, acc[0]); acc[1] = fmaf(wv, pa.y, acc[1]);
                acc[2] = fmaf(wv, pa.z, acc[2]); acc[3] = fmaf(wv, pa.w, acc[3]);
                acc[4] = fmaf(wv, pb.x, acc[4]); acc[5] = fmaf(wv, pb.y, acc[5]);
                acc[6] = fmaf(wv, pb.z, acc[6]); acc[7] = fmaf(wv, pb.w, acc[7]);
            }
            __syncthreads();
        }
#pragma unroll
        for (int vv = 0; vv < 8; ++vv)
            ws[OFF_V + (vq * 32 + vg * 8 + vv) * 384 + m * 6 + a] = acc[vv];
    } else if (blk < 42) {
        float* col = L;
        float* red = L + 256;
        int p = blk - 24, a = p / 3, j = p % 3;
        col[t] = Wdc[(t * 6 + a) * 131 + j];
        __syncthreads();
        int m = t >> 2, q = t & 3;
        const float* wm = Wm0 + m * 256 + q * 64;
        const float* cl = col + q * 64;
        float s = 0.f;
#pragma unroll 8
        for (int i = 0; i < 64; ++i) s = fmaf(wm[i], cl[i], s);
        red[t] = s;
        __syncthreads();
        if (t < 64) {
            float v = (red[t * 4] + red[t * 4 + 1]) + (red[t * 4 + 2] + red[t * 4 + 3]);
            ws[OFF_T2 + t * 18 + a * 3 + j] = v;
        }
    } else if (blk < 106) {
        int b = blk - 42;
        float* red = L;                        // [61][257]
        float acc[61];
#pragma unroll
        for (int i = 0; i < 61; ++i) acc[i] = 0.f;
#pragma unroll 2
        for (int k = 0; k < 8; ++k) {
            int n = t + 256 * k;
            const float* xp = x + (size_t)(b * NPTS + n) * 10;
            float xv[10];
#pragma unroll
            for (int j = 0; j < 5; ++j) {
                float2 v = *(const float2*)(xp + 2 * j);
                xv[2 * j] = v.x; xv[2 * j + 1] = v.y;
            }
            float x0 = xv[0], x1 = xv[1], x2 = xv[2];
            float rn = x0 * x0 + x1 * x1 + x2 * x2;
            float norm = sqrtf(rn);
            float inv = 1.f / (norm + 1e-8f);
            float c2[6];
            c2[0] = fmaxf(x2, 0.f) * inv; c2[1] = fmaxf(-x2, 0.f) * inv;
            c2[2] = fmaxf(x1, 0.f) * inv; c2[3] = fmaxf(-x1, 0.f) * inv;
            c2[4] = fmaxf(x0, 0.f) * inv; c2[5] = fmaxf(-x0, 0.f) * inv;
#pragma unroll
            for (int a = 0; a < 6; ++a) c2[a] *= c2[a];
            float dw = 1.f - (rn - 1.f) * (1.f / 3.f);
            if (dw < 0.f) dw = 0.f;
            if (norm <= 0.f) dw = 0.f;
            float cw[6];
#pragma unroll
            for (int a = 0; a < 6; ++a) cw[a] = c2[a] * dw;
#pragma unroll
            for (int c = 0; c < 10; ++c) {
                float dv = (c < 7) ? xv[3 + c] : xv[c - 7];
#pragma unroll
                for (int a = 0; a < 6; ++a)
                    acc[c * 6 + a] = fmaf(dv, cw[a], acc[c * 6 + a]);
            }
            acc[60] += dw;
        }
#pragma unroll
        for (int i = 0; i < 61; ++i) red[i * 257 + t] = acc[i];
        __syncthreads();
        if (t < 61) {
            float s = 0.f;
#pragma unroll 8
            for (int j = 0; j < 256; ++j) s += red[t * 257 + j];
            ws[OFF_M + b * 61 + t] = s;
        }
    } else {
        for (int g = t; g < 64 * 128; g += 256) ws[OFF_Z + g] = bf1[g & 127];
    }
}

// ---------------------------------------------------------------------------
// k_b1z: unchanged (proven in round 2).
__global__ __launch_bounds__(256) void k_b1z(const float* __restrict__ Wdir,
                                             const float* __restrict__ g1,
                                             const float* __restrict__ b1,
                                             const float* __restrict__ Wdir2,
                                             const float* __restrict__ g2,
                                             const float* __restrict__ b2,
                                             const float* __restrict__ Wf1,
                                             float* __restrict__ ws) {
    __shared__ float L[14496];
    float* Wd  = L;
    float* D2l = L;
    float* Ml  = L + 3904;
    float* wfl = L + 3904;
    float* h1  = L + 8128;
    float* wt2 = L + 12224;
    float* sc  = L + 14304;
    float* of  = L + 14368;
    float* scl = L + 14432;
    float* ofl = L + 14464;
    int blk = blockIdx.x, t = threadIdx.x;
    for (int g = t; g < 64 * 61; g += 256) Ml[g] = ws[OFF_M + g];
    for (int g = t; g < 3840; g += 256) Wd[(g / 60) * 61 + g % 60] = Wdir[g];
    {
        const float* src = Wdir2 + blk * 32 * 64;
        for (int g = t; g < 2048; g += 256) wt2[(g >> 6) * 65 + (g & 63)] = src[g];
    }
    __syncthreads();
    int m = t & 63;
    float Wr[60];
#pragma unroll
    for (int r = 0; r < 60; ++r) Wr[r] = Wd[m * 61 + r];
#pragma unroll
    for (int k = 0; k < 16; ++k) {
        int e0 = t + 256 * k;
        int b = e0 >> 6;
        const float* Mb = Ml + b * 61;
        float s = 0.f;
#pragma unroll
        for (int a = 0; a < 6; ++a)
#pragma unroll
            for (int c = 0; c < 10; ++c)
                s = fmaf(Wr[a * 10 + c], Mb[c * 6 + a], s);
        h1[e0] = s / Mb[60];
    }
    __syncthreads();
    if (t < 64) {
        float s = 0.f, q = 0.f;
#pragma unroll 8
        for (int b = 0; b < 64; ++b) { float v = h1[b * 64 + t]; s += v; q = fmaf(v, v, q); }
        float mean = s * (1.f / 64.f);
        float var = q * (1.f / 64.f) - mean * mean;
        float scale = g1[t] * rsqrtf(var + 1e-5f);
        sc[t] = scale; of[t] = b1[t] - mean * scale;
    }
    __syncthreads();
#pragma unroll
    for (int k = 0; k < 16; ++k) {
        int e0 = t + 256 * k;
        h1[e0] = fmaxf(fmaf(h1[e0], sc[e0 & 63], of[e0 & 63]), 0.f);
    }
    __syncthreads();
    {
        int e_loc = t & 31;
        float wr[64];
#pragma unroll
        for (int mm = 0; mm < 64; ++mm) wr[mm] = wt2[e_loc * 65 + mm];
        int b0 = t >> 5;
#pragma unroll
        for (int k = 0; k < 8; ++k) {
            int b = b0 + 8 * k;
            const float* h = h1 + b * 64;
            float s = 0.f;
#pragma unroll
            for (int mm = 0; mm < 64; ++mm) s = fmaf(h[mm], wr[mm], s);
            D2l[b * 33 + e_loc] = s;
        }
    }
    __syncthreads();
    for (int g = t; g < 128 * 32; g += 256)
        wfl[(g >> 5) * 33 + (g & 31)] = Wf1[(g >> 5) * 256 + blk * 32 + (g & 31)];
    if (t < 32) {
        float s = 0.f, q = 0.f;
#pragma unroll
        for (int b = 0; b < 64; ++b) { float v = D2l[b * 33 + t]; s += v; q = fmaf(v, v, q); }
        float mean = s * (1.f / 64.f);
        float var = q * (1.f / 64.f) - mean * mean;
        int E = blk * 32 + t;
        float scale = g2[E] * rsqrtf(var + 1e-5f);
        scl[t] = scale; ofl[t] = b2[E] - mean * scale;
    }
    __syncthreads();
    for (int g = t; g < 2048; g += 256) {
        int b = g >> 5, e = g & 31;
        D2l[b * 33 + e] = fmaxf(fmaf(D2l[b * 33 + e], scl[e], ofl[e]), 0.f);
    }
    __syncthreads();
    {
        int v = t & 127, half = t >> 7;
        float wv[32];
#pragma unroll
        for (int e = 0; e < 32; ++e) wv[e] = wfl[v * 33 + e];
#pragma unroll
        for (int j = 0; j < 32; ++j) {
            int b = half * 32 + j;
            const float* d = D2l + b * 33;
            float s = 0.f;
#pragma unroll
            for (int e = 0; e < 32; ++e) s = fmaf(d[e], wv[e], s);
            atomicAdd(&ws[OFF_Z + b * 128 + v], s);
        }
    }
}

// ---------------------------------------------------------------------------
// k_c: bn3 partials (unchanged from round 4).
__global__ __launch_bounds__(512) void k_c(const float* __restrict__ x,
                                           float* __restrict__ ws) {
    __shared__ float L[3712];
    float* xl  = L;            // [256][4]
    float* zl  = L + 1024;     // [128]
    float* T2l = L + 1152;     // [1152]
    float* U2l = L + 2304;     // [384]
    float* r2  = L + 2688;     // [1024]
    int blk = blockIdx.x, t = threadIdx.x;
    int b = blk >> 3, c = blk & 7;
    const float* xb = x + (size_t)b * NPTS * 10;
    if (t < 256) {
        const float* xp = xb + (size_t)(c * 256 + t) * 10;
        float2 v01 = *(const float2*)xp;
        xl[t * 4 + 0] = v01.x; xl[t * 4 + 1] = v01.y; xl[t * 4 + 2] = xp[2];
    }
    if (t < 128) zl[t] = ws[OFF_Z + b * 128 + t];
    for (int g = t; g < 1152; g += 512) T2l[g] = ws[OFF_T2 + g];
    __syncthreads();
    if (t < 384) {
        const float* Vt = ws + OFF_V;
        float s0 = 0.f;
#pragma unroll 8
        for (int v = 0; v < 128; ++v) s0 = fmaf(zl[v], Vt[v * 384 + t], s0);
        U2l[t] = s0;
        if (c == 0) ws[OFF_U2 + b * 384 + t] = s0;
    }
    __syncthreads();
    int m = t & 63;
    int g = __builtin_amdgcn_readfirstlane(t >> 6);
    float T[18], U[6];
#pragma unroll
    for (int r = 0; r < 18; ++r) T[r] = T2l[m * 18 + r];
#pragma unroll
    for (int a = 0; a < 6; ++a) U[a] = U2l[m * 6 + a];
    float accS = 0.f, accQ = 0.f;
    const float* xw = xl + g * 32 * 4;
#pragma unroll 4
    for (int i = 0; i < 32; ++i) {
        float x0 = xw[i * 4], x1 = xw[i * 4 + 1], x2 = xw[i * 4 + 2];
        float rn = x0 * x0 + x1 * x1 + x2 * x2;
        float inv = 1.f / (sqrtf(rn) + 1e-8f);
        float c2[6];
        c2[0] = fmaxf(x2, 0.f) * inv; c2[1] = fmaxf(-x2, 0.f) * inv;
        c2[2] = fmaxf(x1, 0.f) * inv; c2[3] = fmaxf(-x1, 0.f) * inv;
        c2[4] = fmaxf(x0, 0.f) * inv; c2[5] = fmaxf(-x0, 0.f) * inv;
        float h = 0.f;
#pragma unroll
        for (int a = 0; a < 6; ++a) {
            float cc = c2[a] * c2[a];
            float ta = fmaf(x0, T[a * 3], fmaf(x1, T[a * 3 + 1], fmaf(x2, T[a * 3 + 2], U[a])));
            h = fmaf(cc, ta, h);
        }
        if (c == 0 && g == 0 && i == 0)
            ws[OFF_H0 + b * 64 + m] = h;
        accS += h;
        accQ = fmaf(h, h, accQ);
    }
    r2[t] = accS; r2[512 + t] = accQ;
    __syncthreads();
    if (t < 64) {
        float s = 0.f;
#pragma unroll
        for (int gg = 0; gg < 8; ++gg) s += r2[gg * 64 + t];
        ws[OFF_GP + blk * 128 + t] = s;
    } else if (t < 128) {
        int mm = t - 64;
        float q = 0.f;
#pragma unroll
        for (int gg = 0; gg < 8; ++gg) q += r2[512 + gg * 64 + mm];
        ws[OFF_GP + blk * 128 + t] = q;
    }
}

// ---------------------------------------------------------------------------
// k_r: replaces the 1-block k_fin (43.9us latency disaster).
// blocks 0..15: tree-reduce GP[512][128] -> GP2[r][128] (16KB coalesced each)
// blocks 16..19: C2 for a 16-batch quarter + (C2-h0) correction -> GP2[16+q]
__global__ __launch_bounds__(256) void k_r(const float* __restrict__ x,
                                           const float* __restrict__ Wcm,
                                           const float* __restrict__ bcm,
                                           float* __restrict__ ws) {
    __shared__ float L[11120];
    int blk = blockIdx.x, t = threadIdx.x;
    if (blk < 16) {
        float* red = L;                       // [256]
        int tt = t & 127, half = t >> 7;
        float s = 0.f;
        const float* gp = ws + OFF_GP + (blk * 32 + half * 16) * 128 + tt;
#pragma unroll
        for (int j = 0; j < 16; ++j) s += gp[j * 128];
        red[half * 128 + tt] = s;
        __syncthreads();
        if (t < 128) ws[OFF_GP2 + blk * 128 + t] = red[t] + red[128 + t];
    } else {
        float* wl = L;             // [64][133] Wcm padded
        float* zl = L + 8512;      // [16][128]
        float* xl = L + 10560;     // [48]
        float* cp = L + 10608;     // [2][4][64]
        int q = blk - 16, b0 = q * 16;
        for (int g = t; g < 64 * 131; g += 256) wl[(g / 131) * 133 + g % 131] = Wcm[g];
        for (int g = t; g < 2048; g += 256) zl[g] = ws[OFF_Z + b0 * 128 + g];
        if (t < 48) xl[t] = x[(size_t)(b0 + t / 3) * NPTS * 10 + t % 3];
        __syncthreads();
        int m = t & 63, bq = t >> 6;
        float cs = 0.f, cq = 0.f;
        const float* w = wl + m * 133;
#pragma unroll
        for (int k = 0; k < 4; ++k) {
            int bl = bq * 4 + k;
            int b = b0 + bl;
            const float* z = zl + bl * 128;   // wave-uniform -> broadcast
            float s = bcm[m];
#pragma unroll 4
            for (int i = 0; i < 128; ++i) s = fmaf(z[i], w[i], s);
            s = fmaf(xl[bl * 3 + 0], w[128], s);
            s = fmaf(xl[bl * 3 + 1], w[129], s);
            s = fmaf(xl[bl * 3 + 2], w[130], s);
            ws[OFF_C2 + b * 64 + m] = s;
            float h0 = ws[OFF_H0 + b * 64 + m];
            cs += s - h0;
            cq += s * s - h0 * h0;
        }
        cp[bq * 64 + m] = cs;
        cp[256 + bq * 64 + m] = cq;
        __syncthreads();
        if (t < 64) {
            ws[OFF_GP2 + (16 + q) * 128 + t] =
                (cp[t] + cp[64 + t]) + (cp[128 + t] + cp[192 + t]);
        } else if (t < 128) {
            int mm = t - 64;
            ws[OFF_GP2 + (16 + q) * 128 + t] =
                (cp[256 + mm] + cp[320 + mm]) + (cp[384 + mm] + cp[448 + mm]);
        }
    }
}

// ---------------------------------------------------------------------------
// k_e: epilogue. Per-block bn3 scale/off from GP2 (identical FP order in
// every block -> deterministic); no serial finalize kernel.
__global__ __launch_bounds__(512) void k_e(const float* __restrict__ x,
                                           const float* __restrict__ g3,
                                           const float* __restrict__ b3,
                                           const float* __restrict__ Wf2,
                                           const float* __restrict__ bf2,
                                           const float* __restrict__ ws,
                                           float* __restrict__ out) {
    __shared__ __attribute__((aligned(16))) float L[6464];
    float* Wl24 = L;           // [64][24]: {T2 at a*4+j, U2 at a*4+3}
    float* Pl   = L + 1536;    // [64][12]: {Wf2[0..6], scale@7, off@8}
    float* C2l  = L + 2304;    // [64]
    float* yp   = L + 2368;    // [256][16]
    int blk = blockIdx.x, t = threadIdx.x;
    int b = blk >> 3;
    for (int g = t; g < 1152; g += 512) {
        int m = g / 18, r = g % 18, a = r / 3, j = r % 3;
        Wl24[m * 24 + a * 4 + j] = ws[OFF_T2 + g];
    }
    if (t < 384)
        Wl24[(t / 6) * 24 + (t % 6) * 4 + 3] = ws[OFF_U2 + b * 384 + t];
    if (t < 448) {
        int m = t / 7, k = t % 7;
        Pl[m * 12 + k] = Wf2[k * 64 + m];
    }
    if (t < 64) {
        float S = 0.f, Q = 0.f;
#pragma unroll
        for (int r = 0; r < 20; ++r) {
            S += ws[OFF_GP2 + r * 128 + t];
            Q += ws[OFF_GP2 + r * 128 + 64 + t];
        }
        float mean = S * (1.f / 131072.f);
        float var = Q * (1.f / 131072.f) - mean * mean;
        float scale = g3[t] * rsqrtf(var + 1e-5f);
        Pl[t * 12 + 7] = scale;
        Pl[t * 12 + 8] = b3[t] - mean * scale;
    }
    if ((blk & 7) == 0 && t < 64) C2l[t] = ws[OFF_C2 + b * 64 + t];
    __syncthreads();

    int p_loc = t >> 1, mh = t & 1;
    int p = blk * 256 + p_loc;
    const float* xp = x + (size_t)p * 10;
    float x0 = xp[0], x1 = xp[1], x2 = xp[2];
    float rn = x0 * x0 + x1 * x1 + x2 * x2;
    float inv = 1.f / (sqrtf(rn) + 1e-8f);
    float c2[6];
    c2[0] = fmaxf(x2, 0.f) * inv; c2[1] = fmaxf(-x2, 0.f) * inv;
    c2[2] = fmaxf(x1, 0.f) * inv; c2[3] = fmaxf(-x1, 0.f) * inv;
    c2[4] = fmaxf(x0, 0.f) * inv; c2[5] = fmaxf(-x0, 0.f) * inv;
#pragma unroll
    for (int a = 0; a < 6; ++a) c2[a] *= c2[a];
    bool c0 = ((p & 2047) == 0);
    float y[7];
#pragma unroll
    for (int k = 0; k < 7; ++k) y[k] = mh ? 0.f : bf2[k];
    int m0 = mh * 32;
#pragma unroll 4
    for (int mm = 0; mm < 32; ++mm) {
        int m = m0 + mm;
        const float4* Wm = (const float4*)(Wl24 + m * 24);
        float h = 0.f;
#pragma unroll
        for (int a = 0; a < 6; ++a) {
            float4 wq = Wm[a];   // {T0,T1,T2,U}
            float ta = fmaf(x0, wq.x, fmaf(x1, wq.y, fmaf(x2, wq.z, wq.w)));
            h = fmaf(c2[a], ta, h);
        }
        if (c0) h = C2l[m];
        const float4* Pm = (const float4*)(Pl + m * 12);
        float4 p0 = Pm[0], p1 = Pm[1];
        float offv = Pl[m * 12 + 8];
        float r = fmaxf(fmaf(h, p1.w, offv), 0.f);
        y[0] = fmaf(r, p0.x, y[0]); y[1] = fmaf(r, p0.y, y[1]);
        y[2] = fmaf(r, p0.z, y[2]); y[3] = fmaf(r, p0.w, y[3]);
        y[4] = fmaf(r, p1.x, y[4]); y[5] = fmaf(r, p1.y, y[5]);
        y[6] = fmaf(r, p1.z, y[6]);
    }
#pragma unroll
    for (int k = 0; k < 7; ++k) yp[p_loc * 16 + mh * 8 + k] = y[k];
    __syncthreads();
    float* op = out + (size_t)blk * 1792;
    for (int g = t; g < 1792; g += 512) {
        int pp = g / 7, k = g % 7;
        float v = yp[pp * 16 + k] + yp[pp * 16 + 8 + k];
        op[g] = 1.f / (1.f + __expf(-v));
    }
}

// ---------------------------------------------------------------------------
extern "C" void kernel_launch(void* const* d_in, const int* in_sizes, int n_in,
                              void* d_out, int out_size, void* d_ws, size_t ws_size,
                              hipStream_t stream) {
    const float* x     = (const float*)d_in[0];
    // d_in[1]=Wc, d_in[2]=bc : dead code in reference
    const float* Wdir  = (const float*)d_in[3];
    const float* g1    = (const float*)d_in[4];
    const float* b1    = (const float*)d_in[5];
    const float* Wdir2 = (const float*)d_in[6];
    const float* g2    = (const float*)d_in[7];
    const float* b2    = (const float*)d_in[8];
    const float* Wf1   = (const float*)d_in[9];
    const float* bf1   = (const float*)d_in[10];
    const float* Wcm   = (const float*)d_in[11];
    const float* bcm   = (const float*)d_in[12];
    const float* Wdc   = (const float*)d_in[13];
    const float* Wm0   = (const float*)d_in[14];
    const float* g3    = (const float*)d_in[15];
    const float* b3    = (const float*)d_in[16];
    const float* Wf2   = (const float*)d_in[17];
    const float* bf2   = (const float*)d_in[18];
    float* ws  = (float*)d_ws;
    float* out = (float*)d_out;

    k_wa <<<107, 256, 0, stream>>>(x, Wm0, Wdc, bf1, ws);
    k_b1z<<<8,   256, 0, stream>>>(Wdir, g1, b1, Wdir2, g2, b2, Wf1, ws);
    k_c  <<<512, 512, 0, stream>>>(x, ws);
    k_r  <<<20,  256, 0, stream>>>(x, Wcm, bcm, ws);
    k_e  <<<512, 512, 0, stream>>>(x, g3, b3, Wf2, bf2, ws, out);
}

// Round 6
// 191.097 us; speedup vs baseline: 1.3337x; 1.0600x over previous
//
#include <hip/hip_runtime.h>
#include <math.h>

// Problem constants
#define BATCH 64
#define NPTS  2048
// ws float offsets (max used: 143360 < 176256)
#define OFF_H0   0       // [64][64] raw h of point 0 (reuses dead M region)
#define OFF_M    0       // [64][61] M[b][c*6+a], Sdw at [b][60] (dead after k_d2)
#define OFF_T2   4096    // [64][18]  T2[m][a*3+j]
#define OFF_GP2  5248    // [12][128] rows 0..7: atomic S/Q by c; rows 8..11: C2 corrections
#define OFF_V    8192    // TRANSPOSED: Vt[v][ma] = [128][384]
#define OFF_WF1T 57344   // Wf1 transposed: [256 e][128 v]
#define OFF_D2P  90112   // [64][256] relu(bn2(d2))
#define OFF_Z    106496  // [64][128] z (written by k_c c==0 blocks)
#define OFF_C2   114688  // [64][64]  center2[b][m] (written by k_r)
#define OFF_U2   118784  // [64][384] U2[b][ma] (written by k_c c==0 blocks)

// ---------------------------------------------------------------------------
// k_wa: blocks 0..23   fold-V as tiled GEMM (a, v-quarter)
//       blocks 24..41  fold-T2 (one (a,j) pair per block)
//       blocks 42..105 stage-A per-batch moments
//       block 106      zero GP2 rows 0..7
//       blocks 107..114 transpose Wf1 -> Wf1t
__global__ __launch_bounds__(256) void k_wa(const float* __restrict__ x,
                                            const float* __restrict__ Wm0,
                                            const float* __restrict__ Wdc,
                                            const float* __restrict__ Wf1,
                                            float* __restrict__ ws) {
    __shared__ __attribute__((aligned(16))) float L[61 * 257];
    int blk = blockIdx.x, t = threadIdx.x;
    if (blk < 24) {
        float* wml = L;            // [64][33]
        float* pl  = L + 2112;     // [32][36]
        int a = blk >> 2, vq = blk & 3;
        int m = t & 63, vg = t >> 6;
        float acc[8];
#pragma unroll
        for (int i = 0; i < 8; ++i) acc[i] = 0.f;
        for (int e0 = 0; e0 < 256; e0 += 32) {
            for (int g = t; g < 2048; g += 256)
                wml[(g >> 5) * 33 + (g & 31)] = Wm0[(g >> 5) * 256 + e0 + (g & 31)];
            for (int g = t; g < 1024; g += 256)
                pl[(g >> 5) * 36 + (g & 31)] =
                    Wdc[((e0 + (g >> 5)) * 6 + a) * 131 + 3 + vq * 32 + (g & 31)];
            __syncthreads();
#pragma unroll
            for (int e = 0; e < 32; ++e) {
                float wv = wml[m * 33 + e];
                const float4* p4 = (const float4*)(pl + e * 36 + vg * 8);
                float4 pa = p4[0], pb = p4[1];
                acc[0] = fmaf(wv, pa.x, acc[0]); acc[1] = fmaf(wv, pa.y, acc[1]);
                acc[2] = fmaf(wv, pa.z, acc[2]); acc[3] = fmaf(wv, pa.w, acc[3]);
                acc[4] = fmaf(wv, pb.x, acc[4]); acc[5] = fmaf(wv, pb.y, acc[5]);
                acc[6] = fmaf(wv, pb.z, acc[6]); acc[7] = fmaf(wv, pb.w, acc[7]);
            }
            __syncthreads();
        }
#pragma unroll
        for (int vv = 0; vv < 8; ++vv)
            ws[OFF_V + (vq * 32 + vg * 8 + vv) * 384 + m * 6 + a] = acc[vv];
    } else if (blk < 42) {
        float* col = L;
        float* red = L + 256;
        int p = blk - 24, a = p / 3, j = p % 3;
        col[t] = Wdc[(t * 6 + a) * 131 + j];
        __syncthreads();
        int m = t >> 2, q = t & 3;
        const float* wm = Wm0 + m * 256 + q * 64;
        const float* cl = col + q * 64;
        float s = 0.f;
#pragma unroll 8
        for (int i = 0; i < 64; ++i) s = fmaf(wm[i], cl[i], s);
        red[t] = s;
        __syncthreads();
        if (t < 64) {
            float v = (red[t * 4] + red[t * 4 + 1]) + (red[t * 4 + 2] + red[t * 4 + 3]);
            ws[OFF_T2 + t * 18 + a * 3 + j] = v;
        }
    } else if (blk < 106) {
        int b = blk - 42;
        float* red = L;                        // [61][257]
        float acc[61];
#pragma unroll
        for (int i = 0; i < 61; ++i) acc[i] = 0.f;
#pragma unroll 2
        for (int k = 0; k < 8; ++k) {
            int n = t + 256 * k;
            const float* xp = x + (size_t)(b * NPTS + n) * 10;
            float xv[10];
#pragma unroll
            for (int j = 0; j < 5; ++j) {
                float2 v = *(const float2*)(xp + 2 * j);
                xv[2 * j] = v.x; xv[2 * j + 1] = v.y;
            }
            float x0 = xv[0], x1 = xv[1], x2 = xv[2];
            float rn = x0 * x0 + x1 * x1 + x2 * x2;
            float norm = sqrtf(rn);
            float inv = 1.f / (norm + 1e-8f);
            float c2[6];
            c2[0] = fmaxf(x2, 0.f) * inv; c2[1] = fmaxf(-x2, 0.f) * inv;
            c2[2] = fmaxf(x1, 0.f) * inv; c2[3] = fmaxf(-x1, 0.f) * inv;
            c2[4] = fmaxf(x0, 0.f) * inv; c2[5] = fmaxf(-x0, 0.f) * inv;
#pragma unroll
            for (int a = 0; a < 6; ++a) c2[a] *= c2[a];
            float dw = 1.f - (rn - 1.f) * (1.f / 3.f);
            if (dw < 0.f) dw = 0.f;
            if (norm <= 0.f) dw = 0.f;
            float cw[6];
#pragma unroll
            for (int a = 0; a < 6; ++a) cw[a] = c2[a] * dw;
#pragma unroll
            for (int c = 0; c < 10; ++c) {
                float dv = (c < 7) ? xv[3 + c] : xv[c - 7];
#pragma unroll
                for (int a = 0; a < 6; ++a)
                    acc[c * 6 + a] = fmaf(dv, cw[a], acc[c * 6 + a]);
            }
            acc[60] += dw;
        }
#pragma unroll
        for (int i = 0; i < 61; ++i) red[i * 257 + t] = acc[i];
        __syncthreads();
        if (t < 61) {
            float s = 0.f;
#pragma unroll 8
            for (int j = 0; j < 256; ++j) s += red[t * 257 + j];
            ws[OFF_M + b * 61 + t] = s;
        }
    } else if (blk == 106) {
        for (int g = t; g < 1024; g += 256) ws[OFF_GP2 + g] = 0.f;
    } else {
        // transpose Wf1[128][256] -> Wf1t[256][128]; block w owns 16 v-rows
        float* slab = L;                       // [16][257]
        int w = blk - 107, v0 = w * 16;
        for (int g = t; g < 4096; g += 256)
            slab[(g >> 8) * 257 + (g & 255)] = Wf1[(v0 + (g >> 8)) * 256 + (g & 255)];
        __syncthreads();
        for (int g = t; g < 4096; g += 256) {
            int e = g >> 4, vl = g & 15;
            ws[OFF_WF1T + e * 128 + v0 + vl] = slab[vl * 257 + e];
        }
    }
}

// ---------------------------------------------------------------------------
// k_d2: replaces the 8-block k_b1z latency pig (75-85us @ 0.27% VALUBusy).
// 64 blocks; each redundantly computes full h1/bn1 (tiny), then d2 + bn2 for
// its 4 owned e-columns. No atomics, no Wf1; ~33KB staging/block, 64-way TLP.
__global__ __launch_bounds__(256) void k_d2(const float* __restrict__ Wdir,
                                            const float* __restrict__ g1,
                                            const float* __restrict__ b1,
                                            const float* __restrict__ Wdir2,
                                            const float* __restrict__ g2,
                                            const float* __restrict__ b2,
                                            float* __restrict__ ws) {
    __shared__ float L[12704];
    float* Wd  = L;            // [64][61]
    float* Ml  = L + 3904;     // [64][61]
    float* h1  = L + 7808;     // [64][65] padded (bank-conflict-free for d2)
    float* wt2 = L + 11968;    // [4][65]
    float* d2l = L + 12228;    // [64][5]
    float* sc  = L + 12548;    // [64]
    float* of  = L + 12612;    // [64]
    float* scl = L + 12676;    // [4]
    float* ofl = L + 12680;    // [4]
    int blk = blockIdx.x, t = threadIdx.x;
    int e_base = blk * 4;
    for (int g = t; g < 64 * 61; g += 256) Ml[g] = ws[OFF_M + g];
    for (int g = t; g < 3840; g += 256) Wd[(g / 60) * 61 + g % 60] = Wdir[g];
    if (t < 256) {
        int el = t >> 6, mm = t & 63;
        wt2[el * 65 + mm] = Wdir2[(e_base + el) * 64 + mm];
    }
    __syncthreads();
    int m = t & 63;
    float Wr[60];
#pragma unroll
    for (int r = 0; r < 60; ++r) Wr[r] = Wd[m * 61 + r];
#pragma unroll
    for (int k = 0; k < 16; ++k) {
        int idx = t + 256 * k;
        int b = idx >> 6;
        const float* Mb = Ml + b * 61;
        float s = 0.f;
#pragma unroll
        for (int a = 0; a < 6; ++a)
#pragma unroll
            for (int c = 0; c < 10; ++c)
                s = fmaf(Wr[a * 10 + c], Mb[c * 6 + a], s);
        h1[b * 65 + m] = s / Mb[60];
    }
    __syncthreads();
    if (t < 64) {
        float s = 0.f, q = 0.f;
#pragma unroll 8
        for (int b = 0; b < 64; ++b) { float v = h1[b * 65 + t]; s += v; q = fmaf(v, v, q); }
        float mean = s * (1.f / 64.f);
        float var = q * (1.f / 64.f) - mean * mean;
        float scale = g1[t] * rsqrtf(var + 1e-5f);
        sc[t] = scale; of[t] = b1[t] - mean * scale;
    }
    __syncthreads();
#pragma unroll
    for (int k = 0; k < 16; ++k) {
        int idx = t + 256 * k;
        int b = idx >> 6;
        h1[b * 65 + m] = fmaxf(fmaf(h1[b * 65 + m], sc[m], of[m]), 0.f);
    }
    __syncthreads();
    // d2 for 4 e-columns: thread (b = t>>2, el = t&3)
    {
        int b = t >> 2, el = t & 3;
        const float* h = h1 + b * 65;
        const float* w = wt2 + el * 65;
        float s = 0.f;
#pragma unroll
        for (int mm = 0; mm < 64; ++mm) s = fmaf(h[mm], w[mm], s);
        d2l[b * 5 + el] = s;
    }
    __syncthreads();
    if (t < 4) {
        float s = 0.f, q = 0.f;
#pragma unroll 8
        for (int b = 0; b < 64; ++b) { float v = d2l[b * 5 + t]; s += v; q = fmaf(v, v, q); }
        float mean = s * (1.f / 64.f);
        float var = q * (1.f / 64.f) - mean * mean;
        int E = e_base + t;
        float scale = g2[E] * rsqrtf(var + 1e-5f);
        scl[t] = scale; ofl[t] = b2[E] - mean * scale;
    }
    __syncthreads();
    {
        int b = t >> 2, el = t & 3;
        float v = fmaxf(fmaf(d2l[b * 5 + el], scl[el], ofl[el]), 0.f);
        ws[OFF_D2P + b * 256 + e_base + el] = v;
    }
}

// ---------------------------------------------------------------------------
// k_c: z recompute (from d2' row x Wf1t) + U2 + bn3 partials (atomic to GP2).
__global__ __launch_bounds__(512) void k_c(const float* __restrict__ x,
                                           const float* __restrict__ bf1,
                                           float* __restrict__ ws) {
    __shared__ float L[4480];
    float* xl    = L;           // [256][4]
    float* zl    = L + 1024;    // [128]
    float* T2l   = L + 1152;    // [1152]
    float* U2l   = L + 2304;    // [384]
    float* r2    = L + 2688;    // [1024]
    float* d2row = L + 3712;    // [256]
    float* zp    = L + 3968;    // [4][128]
    int blk = blockIdx.x, t = threadIdx.x;
    int b = blk >> 3, c = blk & 7;
    const float* xb = x + (size_t)b * NPTS * 10;
    if (t < 256) {
        const float* xp = xb + (size_t)(c * 256 + t) * 10;
        float2 v01 = *(const float2*)xp;
        xl[t * 4 + 0] = v01.x; xl[t * 4 + 1] = v01.y; xl[t * 4 + 2] = xp[2];
        d2row[t] = ws[OFF_D2P + b * 256 + t];
    }
    for (int g = t; g < 1152; g += 512) T2l[g] = ws[OFF_T2 + g];
    __syncthreads();
    // z partials: q = t>>7 owns e in [64q, 64q+64)
    {
        int q = t >> 7, v = t & 127;
        const float* Wt = ws + OFF_WF1T + (q * 64) * 128 + v;
        const float* d = d2row + q * 64;
        float s = 0.f;
#pragma unroll 8
        for (int e = 0; e < 64; ++e) s = fmaf(d[e], Wt[e * 128], s);
        zp[q * 128 + v] = s;
    }
    __syncthreads();
    if (t < 128) {
        float z = bf1[t] + ((zp[t] + zp[128 + t]) + (zp[256 + t] + zp[384 + t]));
        zl[t] = z;
        if (c == 0) ws[OFF_Z + b * 128 + t] = z;
    }
    __syncthreads();
    if (t < 384) {
        const float* Vt = ws + OFF_V;
        float s0 = 0.f;
#pragma unroll 8
        for (int v = 0; v < 128; ++v) s0 = fmaf(zl[v], Vt[v * 384 + t], s0);
        U2l[t] = s0;
        if (c == 0) ws[OFF_U2 + b * 384 + t] = s0;
    }
    __syncthreads();
    int m = t & 63;
    int g = __builtin_amdgcn_readfirstlane(t >> 6);
    float T[18], U[6];
#pragma unroll
    for (int r = 0; r < 18; ++r) T[r] = T2l[m * 18 + r];
#pragma unroll
    for (int a = 0; a < 6; ++a) U[a] = U2l[m * 6 + a];
    float accS = 0.f, accQ = 0.f;
    const float* xw = xl + g * 32 * 4;
#pragma unroll 4
    for (int i = 0; i < 32; ++i) {
        float x0 = xw[i * 4], x1 = xw[i * 4 + 1], x2 = xw[i * 4 + 2];
        float rn = x0 * x0 + x1 * x1 + x2 * x2;
        float inv = 1.f / (sqrtf(rn) + 1e-8f);
        float c2[6];
        c2[0] = fmaxf(x2, 0.f) * inv; c2[1] = fmaxf(-x2, 0.f) * inv;
        c2[2] = fmaxf(x1, 0.f) * inv; c2[3] = fmaxf(-x1, 0.f) * inv;
        c2[4] = fmaxf(x0, 0.f) * inv; c2[5] = fmaxf(-x0, 0.f) * inv;
        float h = 0.f;
#pragma unroll
        for (int a = 0; a < 6; ++a) {
            float cc = c2[a] * c2[a];
            float ta = fmaf(x0, T[a * 3], fmaf(x1, T[a * 3 + 1], fmaf(x2, T[a * 3 + 2], U[a])));
            h = fmaf(cc, ta, h);
        }
        if (c == 0 && g == 0 && i == 0)
            ws[OFF_H0 + b * 64 + m] = h;
        accS += h;
        accQ = fmaf(h, h, accQ);
    }
    r2[t] = accS; r2[512 + t] = accQ;
    __syncthreads();
    if (t < 64) {
        float s = 0.f;
#pragma unroll
        for (int gg = 0; gg < 8; ++gg) s += r2[gg * 64 + t];
        atomicAdd(&ws[OFF_GP2 + c * 128 + t], s);
    } else if (t < 128) {
        int mm = t - 64;
        float q = 0.f;
#pragma unroll
        for (int gg = 0; gg < 8; ++gg) q += r2[512 + gg * 64 + mm];
        atomicAdd(&ws[OFF_GP2 + c * 128 + t], q);
    }
}

// ---------------------------------------------------------------------------
// k_r: C2 for a 16-batch quarter + (C2-h0) correction rows -> GP2[8+q].
__global__ __launch_bounds__(256) void k_r(const float* __restrict__ x,
                                           const float* __restrict__ Wcm,
                                           const float* __restrict__ bcm,
                                           float* __restrict__ ws) {
    __shared__ float L[11120];
    float* wl = L;             // [64][133] Wcm padded
    float* zl = L + 8512;      // [16][128]
    float* xl = L + 10560;     // [48]
    float* cp = L + 10608;     // [2][4][64]
    int q = blockIdx.x, t = threadIdx.x;
    int b0 = q * 16;
    for (int g = t; g < 64 * 131; g += 256) wl[(g / 131) * 133 + g % 131] = Wcm[g];
    for (int g = t; g < 2048; g += 256) zl[g] = ws[OFF_Z + b0 * 128 + g];
    if (t < 48) xl[t] = x[(size_t)(b0 + t / 3) * NPTS * 10 + t % 3];
    __syncthreads();
    int m = t & 63, bq = t >> 6;
    float cs = 0.f, cq = 0.f;
    const float* w = wl + m * 133;
#pragma unroll
    for (int k = 0; k < 4; ++k) {
        int bl = bq * 4 + k;
        int b = b0 + bl;
        const float* z = zl + bl * 128;   // wave-uniform -> broadcast
        float s = bcm[m];
#pragma unroll 4
        for (int i = 0; i < 128; ++i) s = fmaf(z[i], w[i], s);
        s = fmaf(xl[bl * 3 + 0], w[128], s);
        s = fmaf(xl[bl * 3 + 1], w[129], s);
        s = fmaf(xl[bl * 3 + 2], w[130], s);
        ws[OFF_C2 + b * 64 + m] = s;
        float h0 = ws[OFF_H0 + b * 64 + m];
        cs += s - h0;
        cq += s * s - h0 * h0;
    }
    cp[bq * 64 + m] = cs;
    cp[256 + bq * 64 + m] = cq;
    __syncthreads();
    if (t < 64) {
        ws[OFF_GP2 + (8 + q) * 128 + t] =
            (cp[t] + cp[64 + t]) + (cp[128 + t] + cp[192 + t]);
    } else if (t < 128) {
        int mm = t - 64;
        ws[OFF_GP2 + (8 + q) * 128 + t] =
            (cp[256 + mm] + cp[320 + mm]) + (cp[384 + mm] + cp[448 + mm]);
    }
}

// ---------------------------------------------------------------------------
// k_e: epilogue; per-block bn3 scale/off from 12 GP2 rows (identical FP order
// in every block -> deterministic).
__global__ __launch_bounds__(512) void k_e(const float* __restrict__ x,
                                           const float* __restrict__ g3,
                                           const float* __restrict__ b3,
                                           const float* __restrict__ Wf2,
                                           const float* __restrict__ bf2,
                                           const float* __restrict__ ws,
                                           float* __restrict__ out) {
    __shared__ __attribute__((aligned(16))) float L[6464];
    float* Wl24 = L;           // [64][24]: {T2 at a*4+j, U2 at a*4+3}
    float* Pl   = L + 1536;    // [64][12]: {Wf2[0..6], scale@7, off@8}
    float* C2l  = L + 2304;    // [64]
    float* yp   = L + 2368;    // [256][16]
    int blk = blockIdx.x, t = threadIdx.x;
    int b = blk >> 3;
    for (int g = t; g < 1152; g += 512) {
        int m = g / 18, r = g % 18, a = r / 3, j = r % 3;
        Wl24[m * 24 + a * 4 + j] = ws[OFF_T2 + g];
    }
    if (t < 384)
        Wl24[(t / 6) * 24 + (t % 6) * 4 + 3] = ws[OFF_U2 + b * 384 + t];
    if (t < 448) {
        int m = t / 7, k = t % 7;
        Pl[m * 12 + k] = Wf2[k * 64 + m];
    }
    if (t < 64) {
        float S = 0.f, Q = 0.f;
#pragma unroll
        for (int r = 0; r < 12; ++r) {
            S += ws[OFF_GP2 + r * 128 + t];
            Q += ws[OFF_GP2 + r * 128 + 64 + t];
        }
        float mean = S * (1.f / 131072.f);
        float var = Q * (1.f / 131072.f) - mean * mean;
        float scale = g3[t] * rsqrtf(var + 1e-5f);
        Pl[t * 12 + 7] = scale;
        Pl[t * 12 + 8] = b3[t] - mean * scale;
    }
    if ((blk & 7) == 0 && t < 64) C2l[t] = ws[OFF_C2 + b * 64 + t];
    __syncthreads();

    int p_loc = t >> 1, mh = t & 1;
    int p = blk * 256 + p_loc;
    const float* xp = x + (size_t)p * 10;
    float x0 = xp[0], x1 = xp[1], x2 = xp[2];
    float rn = x0 * x0 + x1 * x1 + x2 * x2;
    float inv = 1.f / (sqrtf(rn) + 1e-8f);
    float c2[6];
    c2[0] = fmaxf(x2, 0.f) * inv; c2[1] = fmaxf(-x2, 0.f) * inv;
    c2[2] = fmaxf(x1, 0.f) * inv; c2[3] = fmaxf(-x1, 0.f) * inv;
    c2[4] = fmaxf(x0, 0.f) * inv; c2[5] = fmaxf(-x0, 0.f) * inv;
#pragma unroll
    for (int a = 0; a < 6; ++a) c2[a] *= c2[a];
    bool c0 = ((p & 2047) == 0);
    float y[7];
#pragma unroll
    for (int k = 0; k < 7; ++k) y[k] = mh ? 0.f : bf2[k];
    int m0 = mh * 32;
#pragma unroll 4
    for (int mm = 0; mm < 32; ++mm) {
        int m = m0 + mm;
        const float4* Wm = (const float4*)(Wl24 + m * 24);
        float h = 0.f;
#pragma unroll
        for (int a = 0; a < 6; ++a) {
            float4 wq = Wm[a];   // {T0,T1,T2,U}
            float ta = fmaf(x0, wq.x, fmaf(x1, wq.y, fmaf(x2, wq.z, wq.w)));
            h = fmaf(c2[a], ta, h);
        }
        if (c0) h = C2l[m];
        const float4* Pm = (const float4*)(Pl + m * 12);
        float4 p0 = Pm[0], p1 = Pm[1];
        float offv = Pl[m * 12 + 8];
        float r = fmaxf(fmaf(h, p1.w, offv), 0.f);
        y[0] = fmaf(r, p0.x, y[0]); y[1] = fmaf(r, p0.y, y[1]);
        y[2] = fmaf(r, p0.z, y[2]); y[3] = fmaf(r, p0.w, y[3]);
        y[4] = fmaf(r, p1.x, y[4]); y[5] = fmaf(r, p1.y, y[5]);
        y[6] = fmaf(r, p1.z, y[6]);
    }
#pragma unroll
    for (int k = 0; k < 7; ++k) yp[p_loc * 16 + mh * 8 + k] = y[k];
    __syncthreads();
    float* op = out + (size_t)blk * 1792;
    for (int g = t; g < 1792; g += 512) {
        int pp = g / 7, k = g % 7;
        float v = yp[pp * 16 + k] + yp[pp * 16 + 8 + k];
        op[g] = 1.f / (1.f + __expf(-v));
    }
}

// ---------------------------------------------------------------------------
extern "C" void kernel_launch(void* const* d_in, const int* in_sizes, int n_in,
                              void* d_out, int out_size, void* d_ws, size_t ws_size,
                              hipStream_t stream) {
    const float* x     = (const float*)d_in[0];
    // d_in[1]=Wc, d_in[2]=bc : dead code in reference
    const float* Wdir  = (const float*)d_in[3];
    const float* g1    = (const float*)d_in[4];
    const float* b1    = (const float*)d_in[5];
    const float* Wdir2 = (const float*)d_in[6];
    const float* g2    = (const float*)d_in[7];
    const float* b2    = (const float*)d_in[8];
    const float* Wf1   = (const float*)d_in[9];
    const float* bf1   = (const float*)d_in[10];
    const float* Wcm   = (const float*)d_in[11];
    const float* bcm   = (const float*)d_in[12];
    const float* Wdc   = (const float*)d_in[13];
    const float* Wm0   = (const float*)d_in[14];
    const float* g3    = (const float*)d_in[15];
    const float* b3    = (const float*)d_in[16];
    const float* Wf2   = (const float*)d_in[17];
    const float* bf2   = (const float*)d_in[18];
    float* ws  = (float*)d_ws;
    float* out = (float*)d_out;

    k_wa <<<115, 256, 0, stream>>>(x, Wm0, Wdc, Wf1, ws);
    k_d2 <<<64,  256, 0, stream>>>(Wdir, g1, b1, Wdir2, g2, b2, ws);
    k_c  <<<512, 512, 0, stream>>>(x, bf1, ws);
    k_r  <<<4,   256, 0, stream>>>(x, Wcm, bcm, ws);
    k_e  <<<512, 512, 0, stream>>>(x, g3, b3, Wf2, bf2, ws, out);
}

// Round 7
// 179.217 us; speedup vs baseline: 1.4221x; 1.0663x over previous
//
#include <hip/hip_runtime.h>
#include <math.h>

// Problem constants
#define BATCH 64
#define NPTS  2048
// ws float offsets
#define OFF_M    0       // [64][61] M[b][c*6+a], Sdw at [b][60] (dead after k_d2)
#define OFF_T2   4096    // [64][18]  T2[m][a*3+j]
#define OFF_GP2  5248    // [8][128] atomic S/Q rows by c (corrections folded into row 0)
#define OFF_V    8192    // TRANSPOSED: Vt[v][ma] = [128][384]
#define OFF_WF1T 57344   // Wf1 transposed: [256 e][128 v]
#define OFF_D2P  90112   // [64][256] relu(bn2(d2))
#define OFF_C2   114688  // [64][64]  center2[b][m] (written by k_c c==0 blocks)
#define OFF_U2   118784  // [64][384] U2[b][ma] (written by k_c c==0 blocks)

// ---------------------------------------------------------------------------
// k_wa: blocks 0..23   fold-V as tiled GEMM (a, v-quarter)
//       blocks 24..41  fold-T2 (one (a,j) pair per block)
//       blocks 42..105 stage-A per-batch moments
//       block 106      zero GP2 rows 0..7
//       blocks 107..114 transpose Wf1 -> Wf1t
__global__ __launch_bounds__(256) void k_wa(const float* __restrict__ x,
                                            const float* __restrict__ Wm0,
                                            const float* __restrict__ Wdc,
                                            const float* __restrict__ Wf1,
                                            float* __restrict__ ws) {
    __shared__ __attribute__((aligned(16))) float L[61 * 257];
    int blk = blockIdx.x, t = threadIdx.x;
    if (blk < 24) {
        float* wml = L;            // [64][33]
        float* pl  = L + 2112;     // [32][36]
        int a = blk >> 2, vq = blk & 3;
        int m = t & 63, vg = t >> 6;
        float acc[8];
#pragma unroll
        for (int i = 0; i < 8; ++i) acc[i] = 0.f;
        for (int e0 = 0; e0 < 256; e0 += 32) {
            for (int g = t; g < 2048; g += 256)
                wml[(g >> 5) * 33 + (g & 31)] = Wm0[(g >> 5) * 256 + e0 + (g & 31)];
            for (int g = t; g < 1024; g += 256)
                pl[(g >> 5) * 36 + (g & 31)] =
                    Wdc[((e0 + (g >> 5)) * 6 + a) * 131 + 3 + vq * 32 + (g & 31)];
            __syncthreads();
#pragma unroll
            for (int e = 0; e < 32; ++e) {
                float wv = wml[m * 33 + e];
                const float4* p4 = (const float4*)(pl + e * 36 + vg * 8);
                float4 pa = p4[0], pb = p4[1];
                acc[0] = fmaf(wv, pa.x, acc[0]); acc[1] = fmaf(wv, pa.y, acc[1]);
                acc[2] = fmaf(wv, pa.z, acc[2]); acc[3] = fmaf(wv, pa.w, acc[3]);
                acc[4] = fmaf(wv, pb.x, acc[4]); acc[5] = fmaf(wv, pb.y, acc[5]);
                acc[6] = fmaf(wv, pb.z, acc[6]); acc[7] = fmaf(wv, pb.w, acc[7]);
            }
            __syncthreads();
        }
#pragma unroll
        for (int vv = 0; vv < 8; ++vv)
            ws[OFF_V + (vq * 32 + vg * 8 + vv) * 384 + m * 6 + a] = acc[vv];
    } else if (blk < 42) {
        float* col = L;
        float* red = L + 256;
        int p = blk - 24, a = p / 3, j = p % 3;
        col[t] = Wdc[(t * 6 + a) * 131 + j];
        __syncthreads();
        int m = t >> 2, q = t & 3;
        const float* wm = Wm0 + m * 256 + q * 64;
        const float* cl = col + q * 64;
        float s = 0.f;
#pragma unroll 8
        for (int i = 0; i < 64; ++i) s = fmaf(wm[i], cl[i], s);
        red[t] = s;
        __syncthreads();
        if (t < 64) {
            float v = (red[t * 4] + red[t * 4 + 1]) + (red[t * 4 + 2] + red[t * 4 + 3]);
            ws[OFF_T2 + t * 18 + a * 3 + j] = v;
        }
    } else if (blk < 106) {
        int b = blk - 42;
        float* red = L;                        // [61][257]
        float acc[61];
#pragma unroll
        for (int i = 0; i < 61; ++i) acc[i] = 0.f;
#pragma unroll 2
        for (int k = 0; k < 8; ++k) {
            int n = t + 256 * k;
            const float* xp = x + (size_t)(b * NPTS + n) * 10;
            float xv[10];
#pragma unroll
            for (int j = 0; j < 5; ++j) {
                float2 v = *(const float2*)(xp + 2 * j);
                xv[2 * j] = v.x; xv[2 * j + 1] = v.y;
            }
            float x0 = xv[0], x1 = xv[1], x2 = xv[2];
            float rn = x0 * x0 + x1 * x1 + x2 * x2;
            float norm = sqrtf(rn);
            float inv = 1.f / (norm + 1e-8f);
            float c2[6];
            c2[0] = fmaxf(x2, 0.f) * inv; c2[1] = fmaxf(-x2, 0.f) * inv;
            c2[2] = fmaxf(x1, 0.f) * inv; c2[3] = fmaxf(-x1, 0.f) * inv;
            c2[4] = fmaxf(x0, 0.f) * inv; c2[5] = fmaxf(-x0, 0.f) * inv;
#pragma unroll
            for (int a = 0; a < 6; ++a) c2[a] *= c2[a];
            float dw = 1.f - (rn - 1.f) * (1.f / 3.f);
            if (dw < 0.f) dw = 0.f;
            if (norm <= 0.f) dw = 0.f;
            float cw[6];
#pragma unroll
            for (int a = 0; a < 6; ++a) cw[a] = c2[a] * dw;
#pragma unroll
            for (int c = 0; c < 10; ++c) {
                float dv = (c < 7) ? xv[3 + c] : xv[c - 7];
#pragma unroll
                for (int a = 0; a < 6; ++a)
                    acc[c * 6 + a] = fmaf(dv, cw[a], acc[c * 6 + a]);
            }
            acc[60] += dw;
        }
#pragma unroll
        for (int i = 0; i < 61; ++i) red[i * 257 + t] = acc[i];
        __syncthreads();
        if (t < 61) {
            float s = 0.f;
#pragma unroll 8
            for (int j = 0; j < 256; ++j) s += red[t * 257 + j];
            ws[OFF_M + b * 61 + t] = s;
        }
    } else if (blk == 106) {
        for (int g = t; g < 1024; g += 256) ws[OFF_GP2 + g] = 0.f;
    } else {
        // transpose Wf1[128][256] -> Wf1t[256][128]; block w owns 16 v-rows
        float* slab = L;                       // [16][257]
        int w = blk - 107, v0 = w * 16;
        for (int g = t; g < 4096; g += 256)
            slab[(g >> 8) * 257 + (g & 255)] = Wf1[(v0 + (g >> 8)) * 256 + (g & 255)];
        __syncthreads();
        for (int g = t; g < 4096; g += 256) {
            int e = g >> 4, vl = g & 15;
            ws[OFF_WF1T + e * 128 + v0 + vl] = slab[vl * 257 + e];
        }
    }
}

// ---------------------------------------------------------------------------
// k_d2: 64 blocks; each redundantly computes full h1/bn1 (tiny), then d2 +
// bn2 for its 4 owned e-columns (proven in round 6).
__global__ __launch_bounds__(256) void k_d2(const float* __restrict__ Wdir,
                                            const float* __restrict__ g1,
                                            const float* __restrict__ b1,
                                            const float* __restrict__ Wdir2,
                                            const float* __restrict__ g2,
                                            const float* __restrict__ b2,
                                            float* __restrict__ ws) {
    __shared__ float L[12704];
    float* Wd  = L;            // [64][61]
    float* Ml  = L + 3904;     // [64][61]
    float* h1  = L + 7808;     // [64][65]
    float* wt2 = L + 11968;    // [4][65]
    float* d2l = L + 12228;    // [64][5]
    float* sc  = L + 12548;    // [64]
    float* of  = L + 12612;    // [64]
    float* scl = L + 12676;    // [4]
    float* ofl = L + 12680;    // [4]
    int blk = blockIdx.x, t = threadIdx.x;
    int e_base = blk * 4;
    for (int g = t; g < 64 * 61; g += 256) Ml[g] = ws[OFF_M + g];
    for (int g = t; g < 3840; g += 256) Wd[(g / 60) * 61 + g % 60] = Wdir[g];
    if (t < 256) {
        int el = t >> 6, mm = t & 63;
        wt2[el * 65 + mm] = Wdir2[(e_base + el) * 64 + mm];
    }
    __syncthreads();
    int m = t & 63;
    float Wr[60];
#pragma unroll
    for (int r = 0; r < 60; ++r) Wr[r] = Wd[m * 61 + r];
#pragma unroll
    for (int k = 0; k < 16; ++k) {
        int idx = t + 256 * k;
        int b = idx >> 6;
        const float* Mb = Ml + b * 61;
        float s = 0.f;
#pragma unroll
        for (int a = 0; a < 6; ++a)
#pragma unroll
            for (int c = 0; c < 10; ++c)
                s = fmaf(Wr[a * 10 + c], Mb[c * 6 + a], s);
        h1[b * 65 + m] = s / Mb[60];
    }
    __syncthreads();
    if (t < 64) {
        float s = 0.f, q = 0.f;
#pragma unroll 8
        for (int b = 0; b < 64; ++b) { float v = h1[b * 65 + t]; s += v; q = fmaf(v, v, q); }
        float mean = s * (1.f / 64.f);
        float var = q * (1.f / 64.f) - mean * mean;
        float scale = g1[t] * rsqrtf(var + 1e-5f);
        sc[t] = scale; of[t] = b1[t] - mean * scale;
    }
    __syncthreads();
#pragma unroll
    for (int k = 0; k < 16; ++k) {
        int idx = t + 256 * k;
        int b = idx >> 6;
        h1[b * 65 + m] = fmaxf(fmaf(h1[b * 65 + m], sc[m], of[m]), 0.f);
    }
    __syncthreads();
    {
        int b = t >> 2, el = t & 3;
        const float* h = h1 + b * 65;
        const float* w = wt2 + el * 65;
        float s = 0.f;
#pragma unroll
        for (int mm = 0; mm < 64; ++mm) s = fmaf(h[mm], w[mm], s);
        d2l[b * 5 + el] = s;
    }
    __syncthreads();
    if (t < 4) {
        float s = 0.f, q = 0.f;
#pragma unroll 8
        for (int b = 0; b < 64; ++b) { float v = d2l[b * 5 + t]; s += v; q = fmaf(v, v, q); }
        float mean = s * (1.f / 64.f);
        float var = q * (1.f / 64.f) - mean * mean;
        int E = e_base + t;
        float scale = g2[E] * rsqrtf(var + 1e-5f);
        scl[t] = scale; ofl[t] = b2[E] - mean * scale;
    }
    __syncthreads();
    {
        int b = t >> 2, el = t & 3;
        float v = fmaxf(fmaf(d2l[b * 5 + el], scl[el], ofl[el]), 0.f);
        ws[OFF_D2P + b * 256 + e_base + el] = v;
    }
}

// ---------------------------------------------------------------------------
// k_c: z recompute + U2 + bn3 partials; c==0 blocks additionally compute C2
// (threads 384..447, overlapped with U2) and fold the (C2-h0) point-0
// correction into their GP2 row-0 atomicAdd. k_r eliminated.
__global__ __launch_bounds__(512) void k_c(const float* __restrict__ x,
                                           const float* __restrict__ bf1,
                                           const float* __restrict__ Wcm,
                                           const float* __restrict__ bcm,
                                           float* __restrict__ ws) {
    __shared__ float L[13120];
    float* xl    = L;           // [256][4]
    float* zl    = L + 1024;    // [128]
    float* T2l   = L + 1152;    // [1152]
    float* U2l   = L + 2304;    // [384]
    float* r2    = L + 2688;    // [1024]
    float* d2row = L + 3712;    // [256]
    float* zp    = L + 3968;    // [4][128]
    float* wl    = L + 4480;    // [64][133] Wcm (c==0 only)
    float* C2l   = L + 12992;   // [64]
    float* h0l   = L + 13056;   // [64]
    int blk = blockIdx.x, t = threadIdx.x;
    int b = blk >> 3, c = blk & 7;
    const float* xb = x + (size_t)b * NPTS * 10;
    if (t < 256) {
        const float* xp = xb + (size_t)(c * 256 + t) * 10;
        float2 v01 = *(const float2*)xp;
        xl[t * 4 + 0] = v01.x; xl[t * 4 + 1] = v01.y; xl[t * 4 + 2] = xp[2];
        d2row[t] = ws[OFF_D2P + b * 256 + t];
    }
    for (int g = t; g < 1152; g += 512) T2l[g] = ws[OFF_T2 + g];
    if (c == 0)
        for (int g = t; g < 8384; g += 512) wl[(g / 131) * 133 + g % 131] = Wcm[g];
    __syncthreads();
    // z partials: q = t>>7 owns e in [64q, 64q+64)
    {
        int q = t >> 7, v = t & 127;
        const float* Wt = ws + OFF_WF1T + (q * 64) * 128 + v;
        const float* d = d2row + q * 64;
        float s = 0.f;
#pragma unroll 8
        for (int e = 0; e < 64; ++e) s = fmaf(d[e], Wt[e * 128], s);
        zp[q * 128 + v] = s;
    }
    __syncthreads();
    if (t < 128)
        zl[t] = bf1[t] + ((zp[t] + zp[128 + t]) + (zp[256 + t] + zp[384 + t]));
    __syncthreads();
    if (t < 384) {
        const float* Vt = ws + OFF_V;
        float s0 = 0.f;
#pragma unroll 8
        for (int v = 0; v < 128; ++v) s0 = fmaf(zl[v], Vt[v * 384 + t], s0);
        U2l[t] = s0;
        if (c == 0) ws[OFF_U2 + b * 384 + t] = s0;
    } else if (c == 0 && t < 448) {
        // C2[b][m] (same dot order as the old k_r), overlapped with U2
        int m = t - 384;
        const float* w = wl + m * 133;
        float s = bcm[m];
#pragma unroll 4
        for (int i = 0; i < 128; ++i) s = fmaf(zl[i], w[i], s);
        s = fmaf(xl[0], w[128], s);
        s = fmaf(xl[1], w[129], s);
        s = fmaf(xl[2], w[130], s);
        ws[OFF_C2 + b * 64 + m] = s;
        C2l[m] = s;
    }
    __syncthreads();
    int m = t & 63;
    int g = __builtin_amdgcn_readfirstlane(t >> 6);
    float T[18], U[6];
#pragma unroll
    for (int r = 0; r < 18; ++r) T[r] = T2l[m * 18 + r];
#pragma unroll
    for (int a = 0; a < 6; ++a) U[a] = U2l[m * 6 + a];
    float accS = 0.f, accQ = 0.f;
    const float* xw = xl + g * 32 * 4;
#pragma unroll 4
    for (int i = 0; i < 32; ++i) {
        float x0 = xw[i * 4], x1 = xw[i * 4 + 1], x2 = xw[i * 4 + 2];
        float rn = x0 * x0 + x1 * x1 + x2 * x2;
        float inv = 1.f / (sqrtf(rn) + 1e-8f);
        float c2[6];
        c2[0] = fmaxf(x2, 0.f) * inv; c2[1] = fmaxf(-x2, 0.f) * inv;
        c2[2] = fmaxf(x1, 0.f) * inv; c2[3] = fmaxf(-x1, 0.f) * inv;
        c2[4] = fmaxf(x0, 0.f) * inv; c2[5] = fmaxf(-x0, 0.f) * inv;
        float h = 0.f;
#pragma unroll
        for (int a = 0; a < 6; ++a) {
            float cc = c2[a] * c2[a];
            float ta = fmaf(x0, T[a * 3], fmaf(x1, T[a * 3 + 1], fmaf(x2, T[a * 3 + 2], U[a])));
            h = fmaf(cc, ta, h);
        }
        if (c == 0 && g == 0 && i == 0) h0l[m] = h;   // raw h of point 0 (LDS)
        accS += h;
        accQ = fmaf(h, h, accQ);
    }
    r2[t] = accS; r2[512 + t] = accQ;
    __syncthreads();
    if (t < 64) {
        float s = 0.f;
#pragma unroll
        for (int gg = 0; gg < 8; ++gg) s += r2[gg * 64 + t];
        if (c == 0) s += C2l[t] - h0l[t];             // point-0 correction
        atomicAdd(&ws[OFF_GP2 + c * 128 + t], s);
    } else if (t < 128) {
        int mm = t - 64;
        float q = 0.f;
#pragma unroll
        for (int gg = 0; gg < 8; ++gg) q += r2[512 + gg * 64 + mm];
        if (c == 0) q += C2l[mm] * C2l[mm] - h0l[mm] * h0l[mm];
        atomicAdd(&ws[OFF_GP2 + c * 128 + t], q);
    }
}

// ---------------------------------------------------------------------------
// k_e: epilogue; per-block bn3 scale/off from 8 GP2 rows (identical FP order
// in every block -> deterministic).
__global__ __launch_bounds__(512) void k_e(const float* __restrict__ x,
                                           const float* __restrict__ g3,
                                           const float* __restrict__ b3,
                                           const float* __restrict__ Wf2,
                                           const float* __restrict__ bf2,
                                           const float* __restrict__ ws,
                                           float* __restrict__ out) {
    __shared__ __attribute__((aligned(16))) float L[6464];
    float* Wl24 = L;           // [64][24]: {T2 at a*4+j, U2 at a*4+3}
    float* Pl   = L + 1536;    // [64][12]: {Wf2[0..6], scale@7, off@8}
    float* C2l  = L + 2304;    // [64]
    float* yp   = L + 2368;    // [256][16]
    int blk = blockIdx.x, t = threadIdx.x;
    int b = blk >> 3;
    for (int g = t; g < 1152; g += 512) {
        int m = g / 18, r = g % 18, a = r / 3, j = r % 3;
        Wl24[m * 24 + a * 4 + j] = ws[OFF_T2 + g];
    }
    if (t < 384)
        Wl24[(t / 6) * 24 + (t % 6) * 4 + 3] = ws[OFF_U2 + b * 384 + t];
    if (t < 448) {
        int m = t / 7, k = t % 7;
        Pl[m * 12 + k] = Wf2[k * 64 + m];
    }
    if (t < 64) {
        float S = 0.f, Q = 0.f;
#pragma unroll
        for (int r = 0; r < 8; ++r) {
            S += ws[OFF_GP2 + r * 128 + t];
            Q += ws[OFF_GP2 + r * 128 + 64 + t];
        }
        float mean = S * (1.f / 131072.f);
        float var = Q * (1.f / 131072.f) - mean * mean;
        float scale = g3[t] * rsqrtf(var + 1e-5f);
        Pl[t * 12 + 7] = scale;
        Pl[t * 12 + 8] = b3[t] - mean * scale;
    }
    if ((blk & 7) == 0 && t < 64) C2l[t] = ws[OFF_C2 + b * 64 + t];
    __syncthreads();

    int p_loc = t >> 1, mh = t & 1;
    int p = blk * 256 + p_loc;
    const float* xp = x + (size_t)p * 10;
    float x0 = xp[0], x1 = xp[1], x2 = xp[2];
    float rn = x0 * x0 + x1 * x1 + x2 * x2;
    float inv = 1.f / (sqrtf(rn) + 1e-8f);
    float c2[6];
    c2[0] = fmaxf(x2, 0.f) * inv; c2[1] = fmaxf(-x2, 0.f) * inv;
    c2[2] = fmaxf(x1, 0.f) * inv; c2[3] = fmaxf(-x1, 0.f) * inv;
    c2[4] = fmaxf(x0, 0.f) * inv; c2[5] = fmaxf(-x0, 0.f) * inv;
#pragma unroll
    for (int a = 0; a < 6; ++a) c2[a] *= c2[a];
    bool c0 = ((p & 2047) == 0);
    float y[7];
#pragma unroll
    for (int k = 0; k < 7; ++k) y[k] = mh ? 0.f : bf2[k];
    int m0 = mh * 32;
#pragma unroll 4
    for (int mm = 0; mm < 32; ++mm) {
        int m = m0 + mm;
        const float4* Wm = (const float4*)(Wl24 + m * 24);
        float h = 0.f;
#pragma unroll
        for (int a = 0; a < 6; ++a) {
            float4 wq = Wm[a];   // {T0,T1,T2,U}
            float ta = fmaf(x0, wq.x, fmaf(x1, wq.y, fmaf(x2, wq.z, wq.w)));
            h = fmaf(c2[a], ta, h);
        }
        if (c0) h = C2l[m];
        const float4* Pm = (const float4*)(Pl + m * 12);
        float4 p0 = Pm[0], p1 = Pm[1];
        float offv = Pl[m * 12 + 8];
        float r = fmaxf(fmaf(h, p1.w, offv), 0.f);
        y[0] = fmaf(r, p0.x, y[0]); y[1] = fmaf(r, p0.y, y[1]);
        y[2] = fmaf(r, p0.z, y[2]); y[3] = fmaf(r, p0.w, y[3]);
        y[4] = fmaf(r, p1.x, y[4]); y[5] = fmaf(r, p1.y, y[5]);
        y[6] = fmaf(r, p1.z, y[6]);
    }
#pragma unroll
    for (int k = 0; k < 7; ++k) yp[p_loc * 16 + mh * 8 + k] = y[k];
    __syncthreads();
    float* op = out + (size_t)blk * 1792;
    for (int g = t; g < 1792; g += 512) {
        int pp = g / 7, k = g % 7;
        float v = yp[pp * 16 + k] + yp[pp * 16 + 8 + k];
        op[g] = 1.f / (1.f + __expf(-v));
    }
}

// ---------------------------------------------------------------------------
extern "C" void kernel_launch(void* const* d_in, const int* in_sizes, int n_in,
                              void* d_out, int out_size, void* d_ws, size_t ws_size,
                              hipStream_t stream) {
    const float* x     = (const float*)d_in[0];
    // d_in[1]=Wc, d_in[2]=bc : dead code in reference
    const float* Wdir  = (const float*)d_in[3];
    const float* g1    = (const float*)d_in[4];
    const float* b1    = (const float*)d_in[5];
    const float* Wdir2 = (const float*)d_in[6];
    const float* g2    = (const float*)d_in[7];
    const float* b2    = (const float*)d_in[8];
    const float* Wf1   = (const float*)d_in[9];
    const float* bf1   = (const float*)d_in[10];
    const float* Wcm   = (const float*)d_in[11];
    const float* bcm   = (const float*)d_in[12];
    const float* Wdc   = (const float*)d_in[13];
    const float* Wm0   = (const float*)d_in[14];
    const float* g3    = (const float*)d_in[15];
    const float* b3    = (const float*)d_in[16];
    const float* Wf2   = (const float*)d_in[17];
    const float* bf2   = (const float*)d_in[18];
    float* ws  = (float*)d_ws;
    float* out = (float*)d_out;

    k_wa <<<115, 256, 0, stream>>>(x, Wm0, Wdc, Wf1, ws);
    k_d2 <<<64,  256, 0, stream>>>(Wdir, g1, b1, Wdir2, g2, b2, ws);
    k_c  <<<512, 512, 0, stream>>>(x, bf1, Wcm, bcm, ws);
    k_e  <<<512, 512, 0, stream>>>(x, g3, b3, Wf2, bf2, ws, out);
}

// Round 9
// 165.468 us; speedup vs baseline: 1.5403x; 1.0831x over previous
//
#include <hip/hip_runtime.h>
#include <math.h>

// Problem constants
#define BATCH 64
#define NPTS  2048
// ws float offsets
#define OFF_M    0       // [64][61] M[b][c*6+a], Sdw at [b][60] (dead after k_d2)
#define OFF_T2   4096    // [64][18]  T2[m][a*3+j]
#define OFF_GP2  5248    // [128] S[64], Q[64] (atomic, zeroed by k_wa)
#define OFF_V    8192    // TRANSPOSED: Vt[v][ma] = [128][384]
#define OFF_WF1T 57344   // Wf1 transposed: [256 e][128 v]
#define OFF_D2P  90112   // [64][256] relu(bn2(d2))
#define OFF_C2   114688  // [64][64]  center2[b][m] (written by k_z)
#define OFF_U2   118784  // [64][384] U2[b][ma] (written by k_z)
#define OFF_MOM  143360  // [64][240] per-batch moments: A1[6],A2[18],B1[21],B2[63],B3[126]

// ---------------------------------------------------------------------------
// k_wa: blocks 0..23    fold-V as tiled GEMM (a, v-quarter)
//       blocks 24..41   fold-T2 (one (a,j) pair per block)
//       blocks 42..105  stage-A per-batch moments (M, dw-weighted)
//       block 106       zero GP2
//       blocks 107..114 transpose Wf1 -> Wf1t
//       blocks 115..178 bn3 moments group0: B3[21 pairs][6 xx]   (per batch)
//       blocks 179..242 bn3 moments group1: A1,A2,B1,B2          (per batch)
__global__ __launch_bounds__(256) void k_wa(const float* __restrict__ x,
                                            const float* __restrict__ Wm0,
                                            const float* __restrict__ Wdc,
                                            const float* __restrict__ Wf1,
                                            float* __restrict__ ws) {
    __shared__ __attribute__((aligned(16))) float L[61 * 257];
    int blk = blockIdx.x, t = threadIdx.x;
    if (blk < 24) {
        float* wml = L;            // [64][33]
        float* pl  = L + 2112;     // [32][36]
        int a = blk >> 2, vq = blk & 3;
        int m = t & 63, vg = t >> 6;
        float acc[8];
#pragma unroll
        for (int i = 0; i < 8; ++i) acc[i] = 0.f;
        for (int e0 = 0; e0 < 256; e0 += 32) {
            for (int g = t; g < 2048; g += 256)
                wml[(g >> 5) * 33 + (g & 31)] = Wm0[(g >> 5) * 256 + e0 + (g & 31)];
            for (int g = t; g < 1024; g += 256)
                pl[(g >> 5) * 36 + (g & 31)] =
                    Wdc[((e0 + (g >> 5)) * 6 + a) * 131 + 3 + vq * 32 + (g & 31)];
            __syncthreads();
#pragma unroll
            for (int e = 0; e < 32; ++e) {
                float wv = wml[m * 33 + e];
                const float4* p4 = (const float4*)(pl + e * 36 + vg * 8);
                float4 pa = p4[0], pb = p4[1];
                acc[0] = fmaf(wv, pa.x, acc[0]); acc[1] = fmaf(wv, pa.y, acc[1]);
                acc[2] = fmaf(wv, pa.z, acc[2]); acc[3] = fmaf(wv, pa.w, acc[3]);
                acc[4] = fmaf(wv, pb.x, acc[4]); acc[5] = fmaf(wv, pb.y, acc[5]);
                acc[6] = fmaf(wv, pb.z, acc[6]); acc[7] = fmaf(wv, pb.w, acc[7]);
            }
            __syncthreads();
        }
#pragma unroll
        for (int vv = 0; vv < 8; ++vv)
            ws[OFF_V + (vq * 32 + vg * 8 + vv) * 384 + m * 6 + a] = acc[vv];
    } else if (blk < 42) {
        float* col = L;
        float* red = L + 256;
        int p = blk - 24, a = p / 3, j = p % 3;
        col[t] = Wdc[(t * 6 + a) * 131 + j];
        __syncthreads();
        int m = t >> 2, q = t & 3;
        const float* wm = Wm0 + m * 256 + q * 64;
        const float* cl = col + q * 64;
        float s = 0.f;
#pragma unroll 8
        for (int i = 0; i < 64; ++i) s = fmaf(wm[i], cl[i], s);
        red[t] = s;
        __syncthreads();
        if (t < 64) {
            float v = (red[t * 4] + red[t * 4 + 1]) + (red[t * 4 + 2] + red[t * 4 + 3]);
            ws[OFF_T2 + t * 18 + a * 3 + j] = v;
        }
    } else if (blk < 106) {
        int b = blk - 42;
        float* red = L;                        // [61][257]
        float acc[61];
#pragma unroll
        for (int i = 0; i < 61; ++i) acc[i] = 0.f;
#pragma unroll 2
        for (int k = 0; k < 8; ++k) {
            int n = t + 256 * k;
            const float* xp = x + (size_t)(b * NPTS + n) * 10;
            float xv[10];
#pragma unroll
            for (int j = 0; j < 5; ++j) {
                float2 v = *(const float2*)(xp + 2 * j);
                xv[2 * j] = v.x; xv[2 * j + 1] = v.y;
            }
            float x0 = xv[0], x1 = xv[1], x2 = xv[2];
            float rn = x0 * x0 + x1 * x1 + x2 * x2;
            float norm = sqrtf(rn);
            float inv = 1.f / (norm + 1e-8f);
            float c2[6];
            c2[0] = fmaxf(x2, 0.f) * inv; c2[1] = fmaxf(-x2, 0.f) * inv;
            c2[2] = fmaxf(x1, 0.f) * inv; c2[3] = fmaxf(-x1, 0.f) * inv;
            c2[4] = fmaxf(x0, 0.f) * inv; c2[5] = fmaxf(-x0, 0.f) * inv;
#pragma unroll
            for (int a = 0; a < 6; ++a) c2[a] *= c2[a];
            float dw = 1.f - (rn - 1.f) * (1.f / 3.f);
            if (dw < 0.f) dw = 0.f;
            if (norm <= 0.f) dw = 0.f;
            float cw[6];
#pragma unroll
            for (int a = 0; a < 6; ++a) cw[a] = c2[a] * dw;
#pragma unroll
            for (int c = 0; c < 10; ++c) {
                float dv = (c < 7) ? xv[3 + c] : xv[c - 7];
#pragma unroll
                for (int a = 0; a < 6; ++a)
                    acc[c * 6 + a] = fmaf(dv, cw[a], acc[c * 6 + a]);
            }
            acc[60] += dw;
        }
#pragma unroll
        for (int i = 0; i < 61; ++i) red[i * 257 + t] = acc[i];
        __syncthreads();
        if (t < 61) {
            float s = 0.f;
#pragma unroll 8
            for (int j = 0; j < 256; ++j) s += red[t * 257 + j];
            ws[OFF_M + b * 61 + t] = s;
        }
    } else if (blk == 106) {
        if (t < 128) ws[OFF_GP2 + t] = 0.f;
    } else if (blk < 115) {
        // transpose Wf1[128][256] -> Wf1t[256][128]; block w owns 16 v-rows
        float* slab = L;                       // [16][257]
        int w = blk - 107, v0 = w * 16;
        for (int g = t; g < 4096; g += 256)
            slab[(g >> 8) * 257 + (g & 255)] = Wf1[(v0 + (g >> 8)) * 256 + (g & 255)];
        __syncthreads();
        for (int g = t; g < 4096; g += 256) {
            int e = g >> 4, vl = g & 15;
            ws[OFF_WF1T + e * 128 + v0 + vl] = slab[vl * 257 + e];
        }
    } else if (blk < 179) {
        // ---- bn3 moments group0: B3[p][q], p over 21 (a<=a') pairs, q over
        //      xx pairs (00,01,02,11,12,22). 126 register accumulators.
        int b = blk - 115;
        float* red = L;
        float acc[126];
#pragma unroll
        for (int i = 0; i < 126; ++i) acc[i] = 0.f;
        for (int k = 0; k < 8; ++k) {
            int n = t + 256 * k;
            const float* xp = x + (size_t)(b * NPTS + n) * 10;
            float x0 = xp[0], x1 = xp[1], x2 = xp[2];
            float rn = x0 * x0 + x1 * x1 + x2 * x2;
            float inv = 1.f / (sqrtf(rn) + 1e-8f);
            float c[6];
            c[0] = fmaxf(x2, 0.f) * inv; c[1] = fmaxf(-x2, 0.f) * inv;
            c[2] = fmaxf(x1, 0.f) * inv; c[3] = fmaxf(-x1, 0.f) * inv;
            c[4] = fmaxf(x0, 0.f) * inv; c[5] = fmaxf(-x0, 0.f) * inv;
#pragma unroll
            for (int a = 0; a < 6; ++a) c[a] *= c[a];
            float xx[6] = {x0 * x0, x0 * x1, x0 * x2, x1 * x1, x1 * x2, x2 * x2};
#pragma unroll
            for (int a = 0; a < 6; ++a)
#pragma unroll
                for (int a2 = a; a2 < 6; ++a2) {
                    int p = a * 6 - (a * (a - 1)) / 2 + (a2 - a);
                    float cc = c[a] * c[a2];
#pragma unroll
                    for (int q = 0; q < 6; ++q)
                        acc[p * 6 + q] = fmaf(cc, xx[q], acc[p * 6 + q]);
                }
        }
        // chunked LDS reductions (compile-time register indices)
#pragma unroll
        for (int i = 0; i < 61; ++i) red[i * 257 + t] = acc[i];
        __syncthreads();
        if (t < 61) {
            float s = 0.f;
#pragma unroll 8
            for (int j = 0; j < 256; ++j) s += red[t * 257 + j];
            ws[OFF_MOM + b * 240 + 108 + t] = s;
        }
        __syncthreads();
#pragma unroll
        for (int i = 0; i < 61; ++i) red[i * 257 + t] = acc[61 + i];
        __syncthreads();
        if (t < 61) {
            float s = 0.f;
#pragma unroll 8
            for (int j = 0; j < 256; ++j) s += red[t * 257 + j];
            ws[OFF_MOM + b * 240 + 108 + 61 + t] = s;
        }
        __syncthreads();
#pragma unroll
        for (int i = 0; i < 4; ++i) red[i * 257 + t] = acc[122 + i];
        __syncthreads();
        if (t < 4) {
            float s = 0.f;
#pragma unroll 8
            for (int j = 0; j < 256; ++j) s += red[t * 257 + j];
            ws[OFF_MOM + b * 240 + 108 + 122 + t] = s;
        }
    } else {
        // ---- bn3 moments group1: A1[6], A2[18], B1[21], B2[63] = 108 rows
        int b = blk - 179;
        float* red = L;
        float acc[108];
#pragma unroll
        for (int i = 0; i < 108; ++i) acc[i] = 0.f;
        for (int k = 0; k < 8; ++k) {
            int n = t + 256 * k;
            const float* xp = x + (size_t)(b * NPTS + n) * 10;
            float x0 = xp[0], x1 = xp[1], x2 = xp[2];
            float rn = x0 * x0 + x1 * x1 + x2 * x2;
            float inv = 1.f / (sqrtf(rn) + 1e-8f);
            float c[6];
            c[0] = fmaxf(x2, 0.f) * inv; c[1] = fmaxf(-x2, 0.f) * inv;
            c[2] = fmaxf(x1, 0.f) * inv; c[3] = fmaxf(-x1, 0.f) * inv;
            c[4] = fmaxf(x0, 0.f) * inv; c[5] = fmaxf(-x0, 0.f) * inv;
#pragma unroll
            for (int a = 0; a < 6; ++a) c[a] *= c[a];
#pragma unroll
            for (int a = 0; a < 6; ++a) {
                acc[a] += c[a];
                acc[6 + a * 3 + 0] = fmaf(c[a], x0, acc[6 + a * 3 + 0]);
                acc[6 + a * 3 + 1] = fmaf(c[a], x1, acc[6 + a * 3 + 1]);
                acc[6 + a * 3 + 2] = fmaf(c[a], x2, acc[6 + a * 3 + 2]);
            }
#pragma unroll
            for (int a = 0; a < 6; ++a)
#pragma unroll
                for (int a2 = a; a2 < 6; ++a2) {
                    int p = a * 6 - (a * (a - 1)) / 2 + (a2 - a);
                    float cc = c[a] * c[a2];
                    acc[24 + p] += cc;
                    acc[45 + p * 3 + 0] = fmaf(cc, x0, acc[45 + p * 3 + 0]);
                    acc[45 + p * 3 + 1] = fmaf(cc, x1, acc[45 + p * 3 + 1]);
                    acc[45 + p * 3 + 2] = fmaf(cc, x2, acc[45 + p * 3 + 2]);
                }
        }
#pragma unroll
        for (int i = 0; i < 61; ++i) red[i * 257 + t] = acc[i];
        __syncthreads();
        if (t < 61) {
            float s = 0.f;
#pragma unroll 8
            for (int j = 0; j < 256; ++j) s += red[t * 257 + j];
            ws[OFF_MOM + b * 240 + t] = s;
        }
        __syncthreads();
#pragma unroll
        for (int i = 0; i < 47; ++i) red[i * 257 + t] = acc[61 + i];
        __syncthreads();
        if (t < 47) {
            float s = 0.f;
#pragma unroll 8
            for (int j = 0; j < 256; ++j) s += red[t * 257 + j];
            ws[OFF_MOM + b * 240 + 61 + t] = s;
        }
    }
}

// ---------------------------------------------------------------------------
// k_d2: 64 blocks; each redundantly computes full h1/bn1 (tiny), then d2 +
// bn2 for its 4 owned e-columns (proven in round 6).
__global__ __launch_bounds__(256) void k_d2(const float* __restrict__ Wdir,
                                            const float* __restrict__ g1,
                                            const float* __restrict__ b1,
                                            const float* __restrict__ Wdir2,
                                            const float* __restrict__ g2,
                                            const float* __restrict__ b2,
                                            float* __restrict__ ws) {
    __shared__ float L[12704];
    float* Wd  = L;            // [64][61]
    float* Ml  = L + 3904;     // [64][61]
    float* h1  = L + 7808;     // [64][65]
    float* wt2 = L + 11968;    // [4][65]
    float* d2l = L + 12228;    // [64][5]
    float* sc  = L + 12548;    // [64]
    float* of  = L + 12612;    // [64]
    float* scl = L + 12676;    // [4]
    float* ofl = L + 12680;    // [4]
    int blk = blockIdx.x, t = threadIdx.x;
    int e_base = blk * 4;
    for (int g = t; g < 64 * 61; g += 256) Ml[g] = ws[OFF_M + g];
    for (int g = t; g < 3840; g += 256) Wd[(g / 60) * 61 + g % 60] = Wdir[g];
    if (t < 256) {
        int el = t >> 6, mm = t & 63;
        wt2[el * 65 + mm] = Wdir2[(e_base + el) * 64 + mm];
    }
    __syncthreads();
    int m = t & 63;
    float Wr[60];
#pragma unroll
    for (int r = 0; r < 60; ++r) Wr[r] = Wd[m * 61 + r];
#pragma unroll
    for (int k = 0; k < 16; ++k) {
        int idx = t + 256 * k;
        int b = idx >> 6;
        const float* Mb = Ml + b * 61;
        float s = 0.f;
#pragma unroll
        for (int a = 0; a < 6; ++a)
#pragma unroll
            for (int c = 0; c < 10; ++c)
                s = fmaf(Wr[a * 10 + c], Mb[c * 6 + a], s);
        h1[b * 65 + m] = s / Mb[60];
    }
    __syncthreads();
    if (t < 64) {
        float s = 0.f, q = 0.f;
#pragma unroll 8
        for (int b = 0; b < 64; ++b) { float v = h1[b * 65 + t]; s += v; q = fmaf(v, v, q); }
        float mean = s * (1.f / 64.f);
        float var = q * (1.f / 64.f) - mean * mean;
        float scale = g1[t] * rsqrtf(var + 1e-5f);
        sc[t] = scale; of[t] = b1[t] - mean * scale;
    }
    __syncthreads();
#pragma unroll
    for (int k = 0; k < 16; ++k) {
        int idx = t + 256 * k;
        int b = idx >> 6;
        h1[b * 65 + m] = fmaxf(fmaf(h1[b * 65 + m], sc[m], of[m]), 0.f);
    }
    __syncthreads();
    {
        int b = t >> 2, el = t & 3;
        const float* h = h1 + b * 65;
        const float* w = wt2 + el * 65;
        float s = 0.f;
#pragma unroll
        for (int mm = 0; mm < 64; ++mm) s = fmaf(h[mm], w[mm], s);
        d2l[b * 5 + el] = s;
    }
    __syncthreads();
    if (t < 4) {
        float s = 0.f, q = 0.f;
#pragma unroll 8
        for (int b = 0; b < 64; ++b) { float v = d2l[b * 5 + t]; s += v; q = fmaf(v, v, q); }
        float mean = s * (1.f / 64.f);
        float var = q * (1.f / 64.f) - mean * mean;
        int E = e_base + t;
        float scale = g2[E] * rsqrtf(var + 1e-5f);
        scl[t] = scale; ofl[t] = b2[E] - mean * scale;
    }
    __syncthreads();
    {
        int b = t >> 2, el = t & 3;
        float v = fmaxf(fmaf(d2l[b * 5 + el], scl[el], ofl[el]), 0.f);
        ws[OFF_D2P + b * 256 + e_base + el] = v;
    }
}

// ---------------------------------------------------------------------------
// k_z: replaces k_c. One block per batch: z, U2, C2, then CLOSED-FORM bn3
// S/Q from the per-batch moments (no 131072-point loop), point-0 correction,
// atomicAdd into GP2.
__global__ __launch_bounds__(512) void k_z(const float* __restrict__ x,
                                           const float* __restrict__ bf1,
                                           const float* __restrict__ Wcm,
                                           const float* __restrict__ bcm,
                                           float* __restrict__ ws) {
    __shared__ float L[11252];
    float* d2row = L;          // [256]
    float* T2l   = L + 256;    // [1152]
    float* zp    = L + 1408;   // [4][128]
    float* zl    = L + 1920;   // [128]
    float* U2l   = L + 2048;   // [384]
    float* C2l   = L + 2432;   // [64]
    float* mom   = L + 2496;   // [240]
    float* x0l   = L + 2736;   // [4]
    float* wl    = L + 2740;   // [64][133] Wcm padded
    int b = blockIdx.x, t = threadIdx.x;
    if (t < 256) d2row[t] = ws[OFF_D2P + b * 256 + t];
    for (int g = t; g < 1152; g += 512) T2l[g] = ws[OFF_T2 + g];
    if (t < 234) mom[t] = ws[OFF_MOM + b * 240 + t];
    if (t < 3) x0l[t] = x[(size_t)b * NPTS * 10 + t];
    for (int g = t; g < 8384; g += 512) wl[(g / 131) * 133 + g % 131] = Wcm[g];
    __syncthreads();
    // z partials: q = t>>7 owns e in [64q, 64q+64)
    {
        int q = t >> 7, v = t & 127;
        const float* Wt = ws + OFF_WF1T + (q * 64) * 128 + v;
        const float* d = d2row + q * 64;
        float s = 0.f;
#pragma unroll 8
        for (int e = 0; e < 64; ++e) s = fmaf(d[e], Wt[e * 128], s);
        zp[q * 128 + v] = s;
    }
    __syncthreads();
    if (t < 128)
        zl[t] = bf1[t] + ((zp[t] + zp[128 + t]) + (zp[256 + t] + zp[384 + t]));
    __syncthreads();
    if (t < 384) {
        const float* Vt = ws + OFF_V;
        float s0 = 0.f;
#pragma unroll 8
        for (int v = 0; v < 128; ++v) s0 = fmaf(zl[v], Vt[v * 384 + t], s0);
        U2l[t] = s0;
        ws[OFF_U2 + b * 384 + t] = s0;
    } else if (t < 448) {
        int m = t - 384;
        const float* w = wl + m * 133;
        float s = bcm[m];
#pragma unroll 4
        for (int i = 0; i < 128; ++i) s = fmaf(zl[i], w[i], s);
        s = fmaf(x0l[0], w[128], s);
        s = fmaf(x0l[1], w[129], s);
        s = fmaf(x0l[2], w[130], s);
        ws[OFF_C2 + b * 64 + m] = s;
        C2l[m] = s;
    }
    __syncthreads();
    // closed-form S/Q contraction; one thread per m
    if (t < 64) {
        int m = t;
        float T[18], U[6];
#pragma unroll
        for (int r = 0; r < 18; ++r) T[r] = T2l[m * 18 + r];
#pragma unroll
        for (int a = 0; a < 6; ++a) U[a] = U2l[m * 6 + a];
        // S = sum_a A2[a].T_a + A1[a] U_a
        float S = 0.f;
#pragma unroll
        for (int a = 0; a < 6; ++a) {
            S = fmaf(mom[6 + a * 3 + 0], T[a * 3 + 0], S);
            S = fmaf(mom[6 + a * 3 + 1], T[a * 3 + 1], S);
            S = fmaf(mom[6 + a * 3 + 2], T[a * 3 + 2], S);
            S = fmaf(mom[a], U[a], S);
        }
        // Q = sum_diag term + 2 * sum_offdiag term
        float qd = 0.f, qo = 0.f;
#pragma unroll
        for (int a = 0; a < 6; ++a)
#pragma unroll
            for (int a2 = a; a2 < 6; ++a2) {
                int p = a * 6 - (a * (a - 1)) / 2 + (a2 - a);
                const float* b3 = mom + 108 + p * 6;   // (00,01,02,11,12,22)
                const float* b2 = mom + 45 + p * 3;
                float b1v = mom[24 + p];
                float Ta0 = T[a * 3], Ta1 = T[a * 3 + 1], Ta2 = T[a * 3 + 2];
                float Tb0 = T[a2 * 3], Tb1 = T[a2 * 3 + 1], Tb2 = T[a2 * 3 + 2];
                float w0 = b3[0] * Ta0 + b3[1] * Ta1 + b3[2] * Ta2;
                float w1 = b3[1] * Ta0 + b3[3] * Ta1 + b3[4] * Ta2;
                float w2 = b3[2] * Ta0 + b3[4] * Ta1 + b3[5] * Ta2;
                float term = w0 * Tb0 + w1 * Tb1 + w2 * Tb2;
                float d1 = b2[0] * Ta0 + b2[1] * Ta1 + b2[2] * Ta2;
                float d2_ = b2[0] * Tb0 + b2[1] * Tb1 + b2[2] * Tb2;
                term += U[a2] * d1 + U[a] * d2_ + U[a] * U[a2] * b1v;
                if (a == a2) qd += term; else qo += term;
            }
        float Q = qd + 2.f * qo;
        // point-0 correction: replace raw h0 with C2 in the stats
        float xx0 = x0l[0], xx1 = x0l[1], xx2 = x0l[2];
        float rn = xx0 * xx0 + xx1 * xx1 + xx2 * xx2;
        float inv = 1.f / (sqrtf(rn) + 1e-8f);
        float c2[6];
        c2[0] = fmaxf(xx2, 0.f) * inv; c2[1] = fmaxf(-xx2, 0.f) * inv;
        c2[2] = fmaxf(xx1, 0.f) * inv; c2[3] = fmaxf(-xx1, 0.f) * inv;
        c2[4] = fmaxf(xx0, 0.f) * inv; c2[5] = fmaxf(-xx0, 0.f) * inv;
        float h0 = 0.f;
#pragma unroll
        for (int a = 0; a < 6; ++a) {
            float cc = c2[a] * c2[a];
            float ta = fmaf(xx0, T[a * 3], fmaf(xx1, T[a * 3 + 1], fmaf(xx2, T[a * 3 + 2], U[a])));
            h0 = fmaf(cc, ta, h0);
        }
        float C2v = C2l[m];
        S += C2v - h0;
        Q += C2v * C2v - h0 * h0;
        atomicAdd(&ws[OFF_GP2 + m], S);
        atomicAdd(&ws[OFF_GP2 + 64 + m], Q);
    }
}

// ---------------------------------------------------------------------------
// k_e: epilogue; per-block bn3 scale/off from the single GP2 row (identical
// FP order in every block -> deterministic).
__global__ __launch_bounds__(512) void k_e(const float* __restrict__ x,
                                           const float* __restrict__ g3,
                                           const float* __restrict__ b3,
                                           const float* __restrict__ Wf2,
                                           const float* __restrict__ bf2,
                                           const float* __restrict__ ws,
                                           float* __restrict__ out) {
    __shared__ __attribute__((aligned(16))) float L[6464];
    float* Wl24 = L;           // [64][24]: {T2 at a*4+j, U2 at a*4+3}
    float* Pl   = L + 1536;    // [64][12]: {Wf2[0..6], scale@7, off@8}
    float* C2l  = L + 2304;    // [64]
    float* yp   = L + 2368;    // [256][16]
    int blk = blockIdx.x, t = threadIdx.x;
    int b = blk >> 3;
    for (int g = t; g < 1152; g += 512) {
        int m = g / 18, r = g % 18, a = r / 3, j = r % 3;
        Wl24[m * 24 + a * 4 + j] = ws[OFF_T2 + g];
    }
    if (t < 384)
        Wl24[(t / 6) * 24 + (t % 6) * 4 + 3] = ws[OFF_U2 + b * 384 + t];
    if (t < 448) {
        int m = t / 7, k = t % 7;
        Pl[m * 12 + k] = Wf2[k * 64 + m];
    }
    if (t < 64) {
        float S = ws[OFF_GP2 + t];
        float Q = ws[OFF_GP2 + 64 + t];
        float mean = S * (1.f / 131072.f);
        float var = Q * (1.f / 131072.f) - mean * mean;
        float scale = g3[t] * rsqrtf(var + 1e-5f);
        Pl[t * 12 + 7] = scale;
        Pl[t * 12 + 8] = b3[t] - mean * scale;
    }
    if ((blk & 7) == 0 && t < 64) C2l[t] = ws[OFF_C2 + b * 64 + t];
    __syncthreads();

    int p_loc = t >> 1, mh = t & 1;
    int p = blk * 256 + p_loc;
    const float* xp = x + (size_t)p * 10;
    float x0 = xp[0], x1 = xp[1], x2 = xp[2];
    float rn = x0 * x0 + x1 * x1 + x2 * x2;
    float inv = 1.f / (sqrtf(rn) + 1e-8f);
    float c2[6];
    c2[0] = fmaxf(x2, 0.f) * inv; c2[1] = fmaxf(-x2, 0.f) * inv;
    c2[2] = fmaxf(x1, 0.f) * inv; c2[3] = fmaxf(-x1, 0.f) * inv;
    c2[4] = fmaxf(x0, 0.f) * inv; c2[5] = fmaxf(-x0, 0.f) * inv;
#pragma unroll
    for (int a = 0; a < 6; ++a) c2[a] *= c2[a];
    bool c0 = ((p & 2047) == 0);
    float y[7];
#pragma unroll
    for (int k = 0; k < 7; ++k) y[k] = mh ? 0.f : bf2[k];
    int m0 = mh * 32;
#pragma unroll 4
    for (int mm = 0; mm < 32; ++mm) {
        int m = m0 + mm;
        const float4* Wm = (const float4*)(Wl24 + m * 24);
        float h = 0.f;
#pragma unroll
        for (int a = 0; a < 6; ++a) {
            float4 wq = Wm[a];   // {T0,T1,T2,U}
            float ta = fmaf(x0, wq.x, fmaf(x1, wq.y, fmaf(x2, wq.z, wq.w)));
            h = fmaf(c2[a], ta, h);
        }
        if (c0) h = C2l[m];
        const float4* Pm = (const float4*)(Pl + m * 12);
        float4 p0 = Pm[0], p1 = Pm[1];
        float offv = Pl[m * 12 + 8];
        float r = fmaxf(fmaf(h, p1.w, offv), 0.f);
        y[0] = fmaf(r, p0.x, y[0]); y[1] = fmaf(r, p0.y, y[1]);
        y[2] = fmaf(r, p0.z, y[2]); y[3] = fmaf(r, p0.w, y[3]);
        y[4] = fmaf(r, p1.x, y[4]); y[5] = fmaf(r, p1.y, y[5]);
        y[6] = fmaf(r, p1.z, y[6]);
    }
#pragma unroll
    for (int k = 0; k < 7; ++k) yp[p_loc * 16 + mh * 8 + k] = y[k];
    __syncthreads();
    float* op = out + (size_t)blk * 1792;
    for (int g = t; g < 1792; g += 512) {
        int pp = g / 7, k = g % 7;
        float v = yp[pp * 16 + k] + yp[pp * 16 + 8 + k];
        op[g] = 1.f / (1.f + __expf(-v));
    }
}

// ---------------------------------------------------------------------------
extern "C" void kernel_launch(void* const* d_in, const int* in_sizes, int n_in,
                              void* d_out, int out_size, void* d_ws, size_t ws_size,
                              hipStream_t stream) {
    const float* x     = (const float*)d_in[0];
    // d_in[1]=Wc, d_in[2]=bc : dead code in reference
    const float* Wdir  = (const float*)d_in[3];
    const float* g1    = (const float*)d_in[4];
    const float* b1    = (const float*)d_in[5];
    const float* Wdir2 = (const float*)d_in[6];
    const float* g2    = (const float*)d_in[7];
    const float* b2    = (const float*)d_in[8];
    const float* Wf1   = (const float*)d_in[9];
    const float* bf1   = (const float*)d_in[10];
    const float* Wcm   = (const float*)d_in[11];
    const float* bcm   = (const float*)d_in[12];
    const float* Wdc   = (const float*)d_in[13];
    const float* Wm0   = (const float*)d_in[14];
    const float* g3    = (const float*)d_in[15];
    const float* b3    = (const float*)d_in[16];
    const float* Wf2   = (const float*)d_in[17];
    const float* bf2   = (const float*)d_in[18];
    float* ws  = (float*)d_ws;
    float* out = (float*)d_out;

    k_wa <<<243, 256, 0, stream>>>(x, Wm0, Wdc, Wf1, ws);
    k_d2 <<<64,  256, 0, stream>>>(Wdir, g1, b1, Wdir2, g2, b2, ws);
    k_z  <<<64,  512, 0, stream>>>(x, bf1, Wcm, bcm, ws);
    k_e  <<<512, 512, 0, stream>>>(x, g3, b3, Wf2, bf2, ws, out);
}